// Round 1
// 1344.208 us; speedup vs baseline: 1.4331x; 1.4331x over previous
//
#include <hip/hip_runtime.h>
#include <hip/hip_bf16.h>
#include <math.h>

// Model: 5x (conv1d + bias + LeakyReLU(0.1) + BatchNorm(train-stats)) on
// embedded context, then content attention over a 4096-slot memory, concat
// [emb(x), cfeat, m_out] -> fc -> softmax over 32000 vocab.
// All GEMM-shaped compute in bf16 MFMA (16x16x32), fp32 accumulate.
//
// R1: BN restructured. Old bn_kernel ran C blocks (1.4% occupancy, 337us for
// bn1 alone at 91 GB/s). Now: bn_stats (C x NB ~ 2048 blocks, fp32 partials)
// + bn_finalize (per-channel scale/shift into SS[2C]) + apply FUSED into the
// next consumer (conv staging load / y4 cast / cfeat in-place). BN scratch
// lives in the scores region (dead until attention GEMM).

#define N_SAMP 1024

typedef __bf16 bf16x8 __attribute__((ext_vector_type(8)));
typedef __bf16 bf16x4 __attribute__((ext_vector_type(4)));
typedef float  f32x4  __attribute__((ext_vector_type(4)));

// ---------------------------------------------------------------- reductions
__device__ __forceinline__ float blockReduceMax256(float v) {
    __shared__ float sm[4];
    #pragma unroll
    for (int off = 32; off > 0; off >>= 1) v = fmaxf(v, __shfl_down(v, off, 64));
    if ((threadIdx.x & 63) == 0) sm[threadIdx.x >> 6] = v;
    __syncthreads();
    v = fmaxf(fmaxf(sm[0], sm[1]), fmaxf(sm[2], sm[3]));
    __syncthreads();
    return v;
}

__device__ __forceinline__ float blockReduceSum256(float v) {
    __shared__ float sm[4];
    #pragma unroll
    for (int off = 32; off > 0; off >>= 1) v += __shfl_down(v, off, 64);
    if ((threadIdx.x & 63) == 0) sm[threadIdx.x >> 6] = v;
    __syncthreads();
    v = sm[0] + sm[1] + sm[2] + sm[3];
    __syncthreads();
    return v;
}

// ---------------------------------------------------------------- unified conv
// NORM: apply y = y*SS[ch] + SS[CI+ch] to the input while staging into LDS
// (fuses the previous layer's BatchNorm apply; padding stays 0, matching the
// reference which pads the normalized tensor with 0).
template<int CI, int KW, int STRIDE, int PAD, int LIN, int LOUT, int CO,
         int COG, int LB, int CICH, bool GATHER, bool NORM>
__global__ __launch_bounds__(256)
void conv_lds_kernel(const float* __restrict__ Xg, const int* __restrict__ Cidx,
                     const float* __restrict__ Emb,
                     const float* __restrict__ W, const float* __restrict__ Bias,
                     const float* __restrict__ SS,
                     float* __restrict__ Y) {
    constexpr int CHUNKS = 256 / COG;
    static_assert(COG * CHUNKS == 256, "bad block");
    constexpr int LOUT_PAD = CHUNKS * LB;
    static_assert(LOUT_PAD >= LOUT, "LB too small");
    constexpr int XR = LOUT_PAD * STRIDE + KW;
    constexpr int WROW = CICH * KW + 1;
    static_assert(CI % CICH == 0, "ci chunking");

    __shared__ float Xs[CICH * XR];
    __shared__ float Ws[COG * WROW];
    __shared__ int idx[GATHER ? CI : 1];

    const int n   = blockIdx.y;
    const int co0 = blockIdx.x * COG;
    const int tid = threadIdx.x;
    const int co    = tid % COG;
    const int chunk = tid / COG;
    const int l0 = chunk * LB;

    if constexpr (GATHER) {
        if (tid < CI) idx[tid] = Cidx[n * CI + tid];
        __syncthreads();
    }

    float acc[LB];
    #pragma unroll
    for (int l = 0; l < LB; l++) acc[l] = 0.f;

    for (int c0 = 0; c0 < CI; c0 += CICH) {
        for (int i = tid; i < CICH * XR; i += 256) {
            const int ci_l = i / XR;
            const int j = i - ci_l * XR;
            const int li = j - PAD;
            float v = 0.f;
            if (li >= 0 && li < LIN) {
                if constexpr (GATHER) {
                    v = Emb[(size_t)idx[c0 + ci_l] * 256 + li];
                } else {
                    v = Xg[((size_t)n * CI + c0 + ci_l) * LIN + li];
                    if constexpr (NORM)
                        v = fmaf(v, SS[c0 + ci_l], SS[CI + c0 + ci_l]);
                }
            }
            Xs[i] = v;
        }
        for (int i = tid; i < COG * (CICH * KW); i += 256) {
            const int cw = i / (CICH * KW);
            const int r  = i - cw * (CICH * KW);
            Ws[cw * WROW + r] = W[((size_t)(co0 + cw) * CI + c0) * KW + r];
        }
        __syncthreads();

        #pragma unroll 2
        for (int ci_l = 0; ci_l < CICH; ci_l++) {
            float wv[KW];
            #pragma unroll
            for (int k = 0; k < KW; k++) wv[k] = Ws[co * WROW + ci_l * KW + k];
            constexpr int XW = (LB - 1) * STRIDE + KW;
            float xv[XW];
            #pragma unroll
            for (int j = 0; j < XW; j++) xv[j] = Xs[ci_l * XR + l0 * STRIDE + j];
            #pragma unroll
            for (int l = 0; l < LB; l++)
                #pragma unroll
                for (int k = 0; k < KW; k++)
                    acc[l] = fmaf(xv[l * STRIDE + k], wv[k], acc[l]);
        }
        __syncthreads();
    }

    const float b = Bias[co0 + co];
    float* yr = Y + ((size_t)n * CO + co0 + co) * LOUT;
    #pragma unroll
    for (int l = 0; l < LB; l++) {
        const int ll = l0 + l;
        if (ll < LOUT) {
            float t = acc[l] + b;
            yr[ll] = t > 0.f ? t : 0.1f * t;
        }
    }
}

// ---------------------------------------------------------------- batchnorm
// Stage 1: partial sums over (N,L) chunks. grid (C, NB), 256 threads.
template<int C, int L, int NB>
__global__ __launch_bounds__(256)
void bn_stats_kernel(const float* __restrict__ Y, float2* __restrict__ partial) {
    constexpr int TOTAL = N_SAMP * L;
    constexpr int PER = (TOTAL + NB - 1) / NB;
    const int c = blockIdx.x, nb = blockIdx.y;
    const int start = nb * PER;
    const int end = (start + PER < TOTAL) ? (start + PER) : TOTAL;
    float s = 0.f, s2 = 0.f;
    for (int i = start + (int)threadIdx.x; i < end; i += 256) {
        const int n = i / L, l = i - n * L;
        const float v = Y[((size_t)n * C + c) * L + l];
        s += v;
        s2 = fmaf(v, v, s2);
    }
    #pragma unroll
    for (int off = 32; off > 0; off >>= 1) {
        s  += __shfl_down(s,  off, 64);
        s2 += __shfl_down(s2, off, 64);
    }
    __shared__ float sm1[4], sm2[4];
    if ((threadIdx.x & 63) == 0) { sm1[threadIdx.x >> 6] = s; sm2[threadIdx.x >> 6] = s2; }
    __syncthreads();
    if (threadIdx.x == 0)
        partial[(size_t)c * NB + nb] =
            make_float2(sm1[0] + sm1[1] + sm1[2] + sm1[3],
                        sm2[0] + sm2[1] + sm2[2] + sm2[3]);
}

// Stage 2: reduce NB partials per channel -> scale/shift. grid C, 64 threads.
__global__ __launch_bounds__(64)
void bn_finalize_kernel(const float2* __restrict__ partial, const float* __restrict__ G,
                        const float* __restrict__ Be, float* __restrict__ SS,
                        int C, int NB, float invCnt) {
    const int c = blockIdx.x;
    float s = 0.f, s2 = 0.f;
    for (int i = threadIdx.x; i < NB; i += 64) {
        float2 p = partial[(size_t)c * NB + i];
        s += p.x; s2 += p.y;
    }
    #pragma unroll
    for (int off = 32; off > 0; off >>= 1) {
        s  += __shfl_down(s,  off, 64);
        s2 += __shfl_down(s2, off, 64);
    }
    if (threadIdx.x == 0) {
        double mu  = (double)s * invCnt;
        double var = (double)s2 * invCnt - mu * mu;
        float sc = (float)((double)G[c] / sqrt(var + 1e-5));
        SS[c] = sc;
        SS[C + c] = (float)((double)Be[c] - mu * sc);
    }
}

// ---------------------------------------------------------------- MFMA GEMM
// C[M,N] f32 = act(scale * A[M,K]bf16 · B[N,K]bf16^T + bias[n]).
// Both operands K-major. 128x128 tile, BK=32, 4 waves in 2x2, each wave 64x64
// as 4x4 grid of 16x16x32 MFMAs. Staging via global_load_lds width=16.
__device__ __forceinline__ void gld16(const __bf16* g, __bf16* l) {
    __builtin_amdgcn_global_load_lds(
        (const __attribute__((address_space(1))) unsigned int*)g,
        (__attribute__((address_space(3))) unsigned int*)l, 16, 0, 0);
}

__global__ __launch_bounds__(256)
void mfma_gemm_bt(const __bf16* __restrict__ A, const __bf16* __restrict__ B,
                  const float* __restrict__ bias, float* __restrict__ C,
                  int M, int N, int K, float scale, int leaky) {
    __shared__ __bf16 As[128 * 32];
    __shared__ __bf16 Bs[128 * 32];
    const int tid = threadIdx.x;
    const int row0 = blockIdx.x * 128;
    const int col0 = blockIdx.y * 128;

    // staging: thread t loads 16B; LDS elem offset t*8 (+2048 for second half)
    // -> row t/4 (+64), k-elems (t%4)*8. Wave-uniform base + lane*16. ✓
    const int r  = tid >> 2;
    const int kb = (tid & 3) * 8;
    const __bf16* Ag0 = A + (size_t)(row0 + r) * K + kb;
    const __bf16* Ag1 = A + (size_t)(row0 + r + 64) * K + kb;
    const __bf16* Bg0 = B + (size_t)(col0 + r) * K + kb;
    const __bf16* Bg1 = B + (size_t)(col0 + r + 64) * K + kb;
    __bf16* Al0 = As + tid * 8;
    __bf16* Al1 = As + 2048 + tid * 8;
    __bf16* Bl0 = Bs + tid * 8;
    __bf16* Bl1 = Bs + 2048 + tid * 8;

    const int lane = tid & 63;
    const int wave = tid >> 6;
    const int wy = wave >> 1, wx = wave & 1;
    const int l15 = lane & 15, quad = lane >> 4;

    f32x4 acc[4][4] = {};

    for (int k0 = 0; k0 < K; k0 += 32) {
        __syncthreads();                 // all waves done reading prev tile
        gld16(Ag0 + k0, Al0);
        gld16(Ag1 + k0, Al1);
        gld16(Bg0 + k0, Bl0);
        gld16(Bg1 + k0, Bl1);
        __syncthreads();                 // drains vmcnt -> tiles resident

        bf16x8 af[4], bfr[4];
        #pragma unroll
        for (int mi = 0; mi < 4; mi++)
            af[mi] = *(const bf16x8*)&As[(wy * 64 + mi * 16 + l15) * 32 + quad * 8];
        #pragma unroll
        for (int ni = 0; ni < 4; ni++)
            bfr[ni] = *(const bf16x8*)&Bs[(wx * 64 + ni * 16 + l15) * 32 + quad * 8];
        #pragma unroll
        for (int mi = 0; mi < 4; mi++)
            #pragma unroll
            for (int ni = 0; ni < 4; ni++)
                acc[mi][ni] = __builtin_amdgcn_mfma_f32_16x16x32_bf16(
                    af[mi], bfr[ni], acc[mi][ni], 0, 0, 0);
    }

    // C/D layout: col = lane&15, row = quad*4 + reg
    #pragma unroll
    for (int mi = 0; mi < 4; mi++) {
        #pragma unroll
        for (int ni = 0; ni < 4; ni++) {
            const int col = col0 + wx * 64 + ni * 16 + l15;
            const float bv = bias ? bias[col] : 0.f;
            #pragma unroll
            for (int rg = 0; rg < 4; rg++) {
                const int row = row0 + wy * 64 + mi * 16 + quad * 4 + rg;
                float t = acc[mi][ni][rg] * scale + bv;
                if (leaky) t = t > 0.f ? t : 0.1f * t;
                C[(size_t)row * N + col] = t;
            }
        }
    }
}

// ---------------------------------------------------------------- casts
__global__ __launch_bounds__(256)
void cast_bf16_kernel(const float* __restrict__ in, __bf16* __restrict__ out, int n8) {
    int i = blockIdx.x * 256 + threadIdx.x;
    if (i >= n8) return;
    float4 a = ((const float4*)in)[2 * i];
    float4 b = ((const float4*)in)[2 * i + 1];
    bf16x8 v;
    v[0] = (__bf16)a.x; v[1] = (__bf16)a.y; v[2] = (__bf16)a.z; v[3] = (__bf16)a.w;
    v[4] = (__bf16)b.x; v[5] = (__bf16)b.y; v[6] = (__bf16)b.z; v[7] = (__bf16)b.w;
    ((bf16x8*)out)[i] = v;
}

// bn-apply + cast, for [N, C, L] float -> bf16 (channel = (j/L)%C)
template<int C, int L>
__global__ __launch_bounds__(256)
void bn_apply_cast_kernel(const float* __restrict__ in, __bf16* __restrict__ out,
                          const float* __restrict__ SS, int n8) {
    int i = blockIdx.x * 256 + threadIdx.x;
    if (i >= n8) return;
    float4 a = ((const float4*)in)[2 * i];
    float4 b = ((const float4*)in)[2 * i + 1];
    float vv[8] = {a.x, a.y, a.z, a.w, b.x, b.y, b.z, b.w};
    const int j0 = i * 8;
    bf16x8 v;
    #pragma unroll
    for (int e = 0; e < 8; e++) {
        const int ch = ((j0 + e) / L) % C;
        v[e] = (__bf16)fmaf(vv[e], SS[ch], SS[C + ch]);
    }
    ((bf16x8*)out)[i] = v;
}

// bn-apply in place for cfeat [N, 512] (L=1)
__global__ __launch_bounds__(256)
void bn_apply_c512_kernel(float* __restrict__ Y, const float* __restrict__ SS, int n4) {
    int i = blockIdx.x * 256 + threadIdx.x;
    if (i >= n4) return;
    float4 v = ((float4*)Y)[i];
    const int c = (i * 4) & 511;
    v.x = fmaf(v.x, SS[c + 0], SS[512 + c + 0]);
    v.y = fmaf(v.y, SS[c + 1], SS[512 + c + 1]);
    v.z = fmaf(v.z, SS[c + 2], SS[512 + c + 2]);
    v.w = fmaf(v.w, SS[c + 3], SS[512 + c + 3]);
    ((float4*)Y)[i] = v;
}

// in f32 [R,C] -> out bf16 [C,R]
__global__ __launch_bounds__(256)
void transpose_cast_kernel(const float* __restrict__ in, __bf16* __restrict__ out,
                           int R, int C) {
    __shared__ float t[32][33];
    const int c0 = blockIdx.x * 32, r0 = blockIdx.y * 32;
    const int cc = threadIdx.x & 31, rr = threadIdx.x >> 5;   // rr 0..7
    #pragma unroll
    for (int i = 0; i < 32; i += 8)
        t[rr + i][cc] = in[(size_t)(r0 + rr + i) * C + c0 + cc];
    __syncthreads();
    #pragma unroll
    for (int i = 0; i < 32; i += 8)
        out[(size_t)(c0 + rr + i) * R + r0 + cc] = (__bf16)t[cc][rr + i];
}

// ---------------------------------------------------------------- softmaxes
__global__ __launch_bounds__(256)
void softmax4k_kernel(float* __restrict__ P) {
    float* p = P + (size_t)blockIdx.x * 4096;
    float v[16];
    float mx = -INFINITY;
    #pragma unroll
    for (int i = 0; i < 16; i++) {
        v[i] = p[threadIdx.x + i * 256];
        mx = fmaxf(mx, v[i]);
    }
    mx = blockReduceMax256(mx);
    float s = 0.f;
    #pragma unroll
    for (int i = 0; i < 16; i++) { v[i] = __expf(v[i] - mx); s += v[i]; }
    s = blockReduceSum256(s);
    const float inv = 1.f / s;
    #pragma unroll
    for (int i = 0; i < 16; i++) p[threadIdx.x + i * 256] = v[i] * inv;
}

__global__ __launch_bounds__(256)
void softmax_fc_kernel(float* __restrict__ P) {
    float* p = P + (size_t)blockIdx.x * 32000;
    float mx = -INFINITY;
    for (int i = threadIdx.x; i < 32000; i += 256) mx = fmaxf(mx, p[i]);
    mx = blockReduceMax256(mx);
    float s = 0.f;
    for (int i = threadIdx.x; i < 32000; i += 256) {
        float e = __expf(p[i] - mx);
        p[i] = e; s += e;
    }
    s = blockReduceSum256(s);
    const float inv = 1.f / s;
    for (int i = threadIdx.x; i < 32000; i += 256) p[i] *= inv;
}

// ---------------------------------------------------------------- assemble s (bf16)
__global__ __launch_bounds__(320)
void assemble_s_kernel(const int* __restrict__ X, const float* __restrict__ Emb,
                       const float* __restrict__ Cf, const float* __restrict__ Mo,
                       __bf16* __restrict__ S) {
    const int m = blockIdx.x;
    const int col = threadIdx.x * 4;
    float4 v;
    if (col < 256)      v = *(const float4*)(Emb + (size_t)X[m] * 256 + col);
    else if (col < 768) v = *(const float4*)(Cf + (size_t)m * 512 + (col - 256));
    else                v = *(const float4*)(Mo + (size_t)m * 512 + (col - 768));
    bf16x4 o;
    o[0] = (__bf16)v.x; o[1] = (__bf16)v.y; o[2] = (__bf16)v.z; o[3] = (__bf16)v.w;
    *(bf16x4*)(S + (size_t)m * 1280 + col) = o;
}

// ---------------------------------------------------------------- launch
extern "C" void kernel_launch(void* const* d_in, const int* in_sizes, int n_in,
                              void* d_out, int out_size, void* d_ws, size_t ws_size,
                              hipStream_t stream) {
    const int*   x    = (const int*)d_in[0];
    const int*   c    = (const int*)d_in[1];
    const float* emb  = (const float*)d_in[2];
    const float* w1 = (const float*)d_in[3],  *b1 = (const float*)d_in[4];
    const float* g1 = (const float*)d_in[5],  *be1 = (const float*)d_in[6];
    const float* w2 = (const float*)d_in[7],  *b2 = (const float*)d_in[8];
    const float* g2 = (const float*)d_in[9],  *be2 = (const float*)d_in[10];
    const float* w3 = (const float*)d_in[11], *b3 = (const float*)d_in[12];
    const float* g3 = (const float*)d_in[13], *be3 = (const float*)d_in[14];
    const float* w4 = (const float*)d_in[15], *b4 = (const float*)d_in[16];
    const float* g4 = (const float*)d_in[17], *be4 = (const float*)d_in[18];
    const float* w5 = (const float*)d_in[19], *b5 = (const float*)d_in[20];
    const float* g5 = (const float*)d_in[21], *be5 = (const float*)d_in[22];
    const float* fcW = (const float*)d_in[23], *fcb = (const float*)d_in[24];
    const float* memK = (const float*)d_in[25], *memV = (const float*)d_in[26];
    float* out = (float*)d_out;

    float* ws = (float*)d_ws;
    float* y1     = ws;                       // 1024*32*127 = 4,161,536 f
    float* y2     = ws + 4161536;             // 1024*64*62  = 3,964,928 f
    float* y3     = y1;                       // aliases
    float* y4     = y2;
    float* cfeat  = ws + 8126464;             // 1024*512
    float* scores = ws + 8650752;             // 1024*4096
    float* m_out  = ws + 12845056;            // 1024*512
    // bf16 region starts at float offset 13,369,344 (byte 53,477,376; 16B aligned)
    __bf16* bws      = (__bf16*)(ws + 13369344);
    __bf16* s_bf     = bws;                   // 1,310,720
    __bf16* y4_bf    = bws + 1310720;         // 3,670,016
    __bf16* cfeat_bf = bws + 4980736;         // 524,288
    __bf16* attn_bf  = bws + 5505024;         // 4,194,304
    __bf16* w5_bf    = bws + 9699328;         // 1,835,008
    __bf16* memK_bf  = bws + 11534336;        // 2,097,152
    __bf16* memVT_bf = bws + 13631488;        // 2,097,152
    __bf16* fcWT_bf  = bws + 15728640;        // 40,960,000  (total ~167 MB)

    // BN scratch lives in the scores region (dead until attention GEMM):
    // partial: 4096 float2 max (C*NB <= 2048 here), SS: 2*C floats (<=1024)
    float2* bn_part = (float2*)scores;        // 8192 floats
    float*  SS      = scores + 8192;          // 1024 floats

    // weight conversions (independent of activations)
    transpose_cast_kernel<<<dim3(1000, 40), 256, 0, stream>>>(fcW, fcWT_bf, 1280, 32000);
    transpose_cast_kernel<<<dim3(16, 128), 256, 0, stream>>>(memV, memVT_bf, 4096, 512);
    cast_bf16_kernel<<<1024, 256, 0, stream>>>(memK, memK_bf, 262144);
    cast_bf16_kernel<<<896, 256, 0, stream>>>(w5, w5_bf, 229376);

    // conv stack (pre-BN outputs; BN applied on the consumer's load)
    conv_lds_kernel<64, 8, 2, 2, 256, 127, 32, 32, 16, 16, true, false>
        <<<dim3(1, N_SAMP), 256, 0, stream>>>(nullptr, c, emb, w1, b1, nullptr, y1);
    bn_stats_kernel<32, 127, 64><<<dim3(32, 64), 256, 0, stream>>>(y1, bn_part);
    bn_finalize_kernel<<<32, 64, 0, stream>>>(bn_part, g1, be1, SS, 32, 64,
                                              1.0f / (1024.f * 127.f));
    conv_lds_kernel<32, 8, 2, 2, 127, 62, 64, 32, 8, 16, false, true>
        <<<dim3(2, N_SAMP), 256, 0, stream>>>(y1, nullptr, nullptr, w2, b2, SS, y2);
    bn_stats_kernel<64, 62, 32><<<dim3(64, 32), 256, 0, stream>>>(y2, bn_part);
    bn_finalize_kernel<<<64, 64, 0, stream>>>(bn_part, g2, be2, SS, 64, 32,
                                              1.0f / (1024.f * 62.f));
    conv_lds_kernel<64, 8, 2, 2, 62, 30, 128, 64, 8, 16, false, true>
        <<<dim3(2, N_SAMP), 256, 0, stream>>>(y2, nullptr, nullptr, w3, b3, SS, y3);
    bn_stats_kernel<128, 30, 16><<<dim3(128, 16), 256, 0, stream>>>(y3, bn_part);
    bn_finalize_kernel<<<128, 64, 0, stream>>>(bn_part, g3, be3, SS, 128, 16,
                                               1.0f / (1024.f * 30.f));
    conv_lds_kernel<128, 8, 2, 2, 30, 14, 256, 128, 8, 8, false, true>
        <<<dim3(2, N_SAMP), 256, 0, stream>>>(y3, nullptr, nullptr, w4, b4, SS, y4);
    bn_stats_kernel<256, 14, 8><<<dim3(256, 8), 256, 0, stream>>>(y4, bn_part);
    bn_finalize_kernel<<<256, 64, 0, stream>>>(bn_part, g4, be4, SS, 256, 8,
                                               1.0f / (1024.f * 14.f));

    // conv5 as MFMA GEMM: [1024,3584] x w5[512,3584]^T + b5, leaky
    // (bn4 apply fused into the bf16 cast of y4)
    bn_apply_cast_kernel<256, 14><<<1792, 256, 0, stream>>>(y4, y4_bf, SS, 458752);
    mfma_gemm_bt<<<dim3(8, 4), 256, 0, stream>>>(y4_bf, w5_bf, b5, cfeat,
                                                 1024, 512, 3584, 1.0f, 1);
    bn_stats_kernel<512, 1, 1><<<dim3(512, 1), 256, 0, stream>>>(cfeat, bn_part);
    bn_finalize_kernel<<<512, 64, 0, stream>>>(bn_part, g5, be5, SS, 512, 1,
                                               1.0f / 1024.f);
    bn_apply_c512_kernel<<<512, 256, 0, stream>>>(cfeat, SS, 131072);

    // attention over memory
    cast_bf16_kernel<<<256, 256, 0, stream>>>(cfeat, cfeat_bf, 65536);
    mfma_gemm_bt<<<dim3(8, 32), 256, 0, stream>>>(cfeat_bf, memK_bf, nullptr, scores,
                                                  1024, 4096, 512, 0.04419417382415922f, 0);
    softmax4k_kernel<<<1024, 256, 0, stream>>>(scores);
    cast_bf16_kernel<<<2048, 256, 0, stream>>>(scores, attn_bf, 524288);
    mfma_gemm_bt<<<dim3(8, 4), 256, 0, stream>>>(attn_bf, memVT_bf, nullptr, m_out,
                                                 1024, 512, 4096, 1.0f, 0);

    // concat + fc + softmax
    assemble_s_kernel<<<1024, 320, 0, stream>>>(x, emb, cfeat, m_out, s_bf);
    mfma_gemm_bt<<<dim3(8, 250), 256, 0, stream>>>(s_bf, fcWT_bf, fcb, out,
                                                   1024, 32000, 1280, 1.0f, 0);
    softmax_fc_kernel<<<1024, 256, 0, stream>>>(out);
}

// Round 2
// 1080.112 us; speedup vs baseline: 1.7835x; 1.2445x over previous
//
#include <hip/hip_runtime.h>
#include <hip/hip_bf16.h>
#include <math.h>

// Model: 5x (conv1d + bias + LeakyReLU(0.1) + BatchNorm(train-stats)) on
// embedded context, then content attention over a 4096-slot memory, concat
// [emb(x), cfeat, m_out] -> fc -> softmax over 32000 vocab.
//
// R2: all convs moved to bf16 MFMA GEMM.
//  - activations in [n, l, c] layout; im2col K-order = (kw outer, ci inner)
//    so im2col reads/writes are contiguous; weights pre-transformed to match.
//  - conv1 has NO materialized im2col: Gt[n, li(pad), ci] bf16 is a strided
//    view (lda=128, block-base ablk=16768, one n per 128-row tile).
//  - GEMM: column-masked stores (real-N stride), lda/ablk params, optional
//    XCD-aware block swizzle (fc GEMM: 8 row-blocks of each B-tile were
//    landing on 8 different XCDs -> 8x L3 refetch of 82MB fcWT).
//  - BN: stats (NLC layout, wide grids) + finalize -> SS; apply fused into
//    the next im2col / cast.

#define N_SAMP 1024

typedef __bf16 bf16x8 __attribute__((ext_vector_type(8)));
typedef __bf16 bf16x4 __attribute__((ext_vector_type(4)));
typedef float  f32x4  __attribute__((ext_vector_type(4)));

// ---------------------------------------------------------------- reductions
__device__ __forceinline__ float blockReduceMax256(float v) {
    __shared__ float sm[4];
    #pragma unroll
    for (int off = 32; off > 0; off >>= 1) v = fmaxf(v, __shfl_down(v, off, 64));
    if ((threadIdx.x & 63) == 0) sm[threadIdx.x >> 6] = v;
    __syncthreads();
    v = fmaxf(fmaxf(sm[0], sm[1]), fmaxf(sm[2], sm[3]));
    __syncthreads();
    return v;
}

__device__ __forceinline__ float blockReduceSum256(float v) {
    __shared__ float sm[4];
    #pragma unroll
    for (int off = 32; off > 0; off >>= 1) v += __shfl_down(v, off, 64);
    if ((threadIdx.x & 63) == 0) sm[threadIdx.x >> 6] = v;
    __syncthreads();
    v = sm[0] + sm[1] + sm[2] + sm[3];
    __syncthreads();
    return v;
}

// ------------------------------------------------------- conv1 input prep
// Gt[n, 2+li, ci] = Emb[c[n,ci]*256 + li], li in [0,256); rows 0,1 and
// 258..261 are zero (PAD=2 left, up to +3 right for l=127 tail). 262 rows/n.
__global__ __launch_bounds__(256)
void gather_tr_kernel(const int* __restrict__ Cidx, const float* __restrict__ Emb,
                      __bf16* __restrict__ Gt) {
    const int n = blockIdx.x;
    __shared__ int idx[64];
    __shared__ float t[64][65];
    if (threadIdx.x < 64) idx[threadIdx.x] = Cidx[n * 64 + threadIdx.x];
    __bf16* g = Gt + (size_t)n * (262 * 64);
    for (int i = threadIdx.x; i < 6 * 64; i += 256) {
        int r = i >> 6;
        int phys = (r < 2) ? r : r + 256;   // 0,1,258,259,260,261
        g[(size_t)phys * 64 + (i & 63)] = (__bf16)0.f;
    }
    for (int c0 = 0; c0 < 256; c0 += 64) {
        __syncthreads();
        for (int i = threadIdx.x; i < 4096; i += 256) {
            int ci = i >> 6, li = i & 63;
            t[ci][li] = Emb[(size_t)idx[ci] * 256 + c0 + li];
        }
        __syncthreads();
        for (int i = threadIdx.x; i < 4096; i += 256) {
            int li = i >> 6, ci = i & 63;
            g[(size_t)(2 + c0 + li) * 64 + ci] = (__bf16)t[ci][li];
        }
    }
}

// ------------------------------------------------------- weight transform
// W [CO, CI, KW] fp32 -> O [COP rows, K=KW*CI] bf16, kidx = k*CI+ci, pad 0.
__global__ __launch_bounds__(256)
void wt_kernel(const float* __restrict__ W, __bf16* __restrict__ O,
               int CO, int CI, int KW) {
    const int co = blockIdx.x;
    const int K = CI * KW;
    for (int i = threadIdx.x; i < K; i += 256) {
        int k = i / CI, ci = i - k * CI;
        O[(size_t)co * K + i] =
            (co < CO) ? (__bf16)W[((size_t)co * CI + ci) * KW + k] : (__bf16)0.f;
    }
}

// ------------------------------------------------------- im2col (+BN apply)
// Y [N*? rows (n*LSTR+li), CI] fp32 -> A [(n*LOUT+l), KW=8 * CI] bf16
// A[(m), k*CI+ci] = bn(Y[n, li=2l-2+k, ci]) or 0 if OOB. STRIDE=2, PAD=2.
template<int CI, int LIN, int LSTR, int LOUT>
__global__ __launch_bounds__(256)
void im2col_kernel(const float* __restrict__ Y, const float* __restrict__ SS,
                   __bf16* __restrict__ A) {
    constexpr int GPR = CI / 8;
    const int TOT = N_SAMP * LOUT * 8 * GPR;
    int g = blockIdx.x * 256 + threadIdx.x;
    if (g >= TOT) return;
    const int ci0 = (g & (GPR - 1)) * 8;
    const int t = g / GPR;
    const int k = t & 7;
    const int m = t >> 3;
    const int l = m % LOUT;
    const int n = m / LOUT;
    const int li = l * 2 - 2 + k;
    bf16x8 o = {};
    if (li >= 0 && li < LIN) {
        const float* src = Y + ((size_t)n * LSTR + li) * CI + ci0;
        float4 a = *(const float4*)src;
        float4 b = *(const float4*)(src + 4);
        float vv[8] = {a.x, a.y, a.z, a.w, b.x, b.y, b.z, b.w};
        #pragma unroll
        for (int e = 0; e < 8; e++)
            o[e] = (__bf16)fmaf(vv[e], SS[ci0 + e], SS[CI + ci0 + e]);
    }
    *(bf16x8*)(A + (size_t)g * 8) = o;
}

// ---------------------------------------------------------------- batchnorm
// NLC layout stats: Y rows (n*LSTR + l), C cols; valid (n,l): n<1024, l<LOUT.
template<int C, int LOUT, int LSTR, int NB>
__global__ __launch_bounds__(256)
void bn_stats_nlc_kernel(const float* __restrict__ Y, float2* __restrict__ partial) {
    constexpr int RPT = 256 / C;
    constexpr int M = N_SAMP * LOUT;
    const int col = threadIdx.x & (C - 1);
    const int rofs = threadIdx.x / C;
    float s = 0.f, s2 = 0.f;
    for (int m = blockIdx.x * RPT + rofs; m < M; m += NB * RPT) {
        float v;
        if constexpr (LSTR == LOUT) {
            v = Y[(size_t)m * C + col];
        } else {
            int n = m / LOUT, l = m - n * LOUT;
            v = Y[((size_t)n * LSTR + l) * C + col];
        }
        s += v; s2 = fmaf(v, v, s2);
    }
    __shared__ float sm[256], sm2[256];
    sm[threadIdx.x] = s; sm2[threadIdx.x] = s2;
    __syncthreads();
    #pragma unroll
    for (int off = 128; off >= C; off >>= 1) {
        if (threadIdx.x < off) {
            sm[threadIdx.x] += sm[threadIdx.x + off];
            sm2[threadIdx.x] += sm2[threadIdx.x + off];
        }
        __syncthreads();
    }
    if (threadIdx.x < C)
        partial[(size_t)blockIdx.x * C + threadIdx.x] =
            make_float2(sm[threadIdx.x], sm2[threadIdx.x]);
}

__global__ __launch_bounds__(64)
void bn_finalize_nlc_kernel(const float2* __restrict__ partial,
                            const float* __restrict__ G, const float* __restrict__ Be,
                            float* __restrict__ SS, int C, int NB, float invCnt) {
    const int c = blockIdx.x;
    float s = 0.f, s2 = 0.f;
    for (int i = threadIdx.x; i < NB; i += 64) {
        float2 p = partial[(size_t)i * C + c];
        s += p.x; s2 += p.y;
    }
    #pragma unroll
    for (int off = 32; off > 0; off >>= 1) {
        s  += __shfl_down(s,  off, 64);
        s2 += __shfl_down(s2, off, 64);
    }
    if (threadIdx.x == 0) {
        double mu  = (double)s * invCnt;
        double var = (double)s2 * invCnt - mu * mu;
        float sc = (float)((double)G[c] / sqrt(var + 1e-5));
        SS[c] = sc;
        SS[C + c] = (float)((double)Be[c] - mu * sc);
    }
}

// cfeat stats ([1024, 512], one block per channel — tiny tensor)
template<int C, int L, int NB>
__global__ __launch_bounds__(256)
void bn_stats_kernel(const float* __restrict__ Y, float2* __restrict__ partial) {
    constexpr int TOTAL = N_SAMP * L;
    constexpr int PER = (TOTAL + NB - 1) / NB;
    const int c = blockIdx.x, nb = blockIdx.y;
    const int start = nb * PER;
    const int end = (start + PER < TOTAL) ? (start + PER) : TOTAL;
    float s = 0.f, s2 = 0.f;
    for (int i = start + (int)threadIdx.x; i < end; i += 256) {
        const int n = i / L, l = i - n * L;
        const float v = Y[((size_t)n * C + c) * L + l];
        s += v;
        s2 = fmaf(v, v, s2);
    }
    #pragma unroll
    for (int off = 32; off > 0; off >>= 1) {
        s  += __shfl_down(s,  off, 64);
        s2 += __shfl_down(s2, off, 64);
    }
    __shared__ float sm1[4], sm2[4];
    if ((threadIdx.x & 63) == 0) { sm1[threadIdx.x >> 6] = s; sm2[threadIdx.x >> 6] = s2; }
    __syncthreads();
    if (threadIdx.x == 0)
        partial[(size_t)c * NB + nb] =
            make_float2(sm1[0] + sm1[1] + sm1[2] + sm1[3],
                        sm2[0] + sm2[1] + sm2[2] + sm2[3]);
}

__global__ __launch_bounds__(64)
void bn_finalize_kernel(const float2* __restrict__ partial, const float* __restrict__ G,
                        const float* __restrict__ Be, float* __restrict__ SS,
                        int C, int NB, float invCnt) {
    const int c = blockIdx.x;
    float s = 0.f, s2 = 0.f;
    for (int i = threadIdx.x; i < NB; i += 64) {
        float2 p = partial[(size_t)c * NB + i];
        s += p.x; s2 += p.y;
    }
    #pragma unroll
    for (int off = 32; off > 0; off >>= 1) {
        s  += __shfl_down(s,  off, 64);
        s2 += __shfl_down(s2, off, 64);
    }
    if (threadIdx.x == 0) {
        double mu  = (double)s * invCnt;
        double var = (double)s2 * invCnt - mu * mu;
        float sc = (float)((double)G[c] / sqrt(var + 1e-5));
        SS[c] = sc;
        SS[C + c] = (float)((double)Be[c] - mu * sc);
    }
}

// ---------------------------------------------------------------- MFMA GEMM
// C[M,N] f32 = act(scale * A · B^T + bias[n]), A rows at bx*ablk + r*lda
// (overlapping rows allowed -> conv1 strided-view im2col). Stores masked to
// col < N with C-stride N. swz: XCD-aware block remap (requires G%8==0).
__device__ __forceinline__ void gld16(const __bf16* g, __bf16* l) {
    __builtin_amdgcn_global_load_lds(
        (const __attribute__((address_space(1))) unsigned int*)g,
        (__attribute__((address_space(3))) unsigned int*)l, 16, 0, 0);
}

__global__ __launch_bounds__(256)
void mfma_gemm_bt(const __bf16* __restrict__ A, const __bf16* __restrict__ B,
                  const float* __restrict__ bias, float* __restrict__ C,
                  int M, int N, int K, int lda, long long ablk,
                  float scale, int leaky, int swz) {
    __shared__ __bf16 As[128 * 32];
    __shared__ __bf16 Bs[128 * 32];
    const int tid = threadIdx.x;
    int bx = blockIdx.x, by = blockIdx.y;
    if (swz) {
        const int gx = gridDim.x;
        const int G = gx * gridDim.y;
        const int bid = by * gx + bx;
        const int fid = (bid & 7) * (G >> 3) + (bid >> 3);
        bx = fid % gx; by = fid / gx;
    }
    const int row0 = bx * 128;
    const int col0 = by * 128;

    const int r  = tid >> 2;
    const int kb = (tid & 3) * 8;
    const __bf16* Ab = A + (size_t)bx * ablk;
    const __bf16* Ag0 = Ab + (size_t)r * lda + kb;
    const __bf16* Ag1 = Ab + (size_t)(r + 64) * lda + kb;
    const __bf16* Bg0 = B + (size_t)(col0 + r) * K + kb;
    const __bf16* Bg1 = B + (size_t)(col0 + r + 64) * K + kb;
    __bf16* Al0 = As + tid * 8;
    __bf16* Al1 = As + 2048 + tid * 8;
    __bf16* Bl0 = Bs + tid * 8;
    __bf16* Bl1 = Bs + 2048 + tid * 8;

    const int lane = tid & 63;
    const int wave = tid >> 6;
    const int wy = wave >> 1, wx = wave & 1;
    const int l15 = lane & 15, quad = lane >> 4;

    f32x4 acc[4][4] = {};

    for (int k0 = 0; k0 < K; k0 += 32) {
        __syncthreads();
        gld16(Ag0 + k0, Al0);
        gld16(Ag1 + k0, Al1);
        gld16(Bg0 + k0, Bl0);
        gld16(Bg1 + k0, Bl1);
        __syncthreads();

        bf16x8 af[4], bfr[4];
        #pragma unroll
        for (int mi = 0; mi < 4; mi++)
            af[mi] = *(const bf16x8*)&As[(wy * 64 + mi * 16 + l15) * 32 + quad * 8];
        #pragma unroll
        for (int ni = 0; ni < 4; ni++)
            bfr[ni] = *(const bf16x8*)&Bs[(wx * 64 + ni * 16 + l15) * 32 + quad * 8];
        #pragma unroll
        for (int mi = 0; mi < 4; mi++)
            #pragma unroll
            for (int ni = 0; ni < 4; ni++)
                acc[mi][ni] = __builtin_amdgcn_mfma_f32_16x16x32_bf16(
                    af[mi], bfr[ni], acc[mi][ni], 0, 0, 0);
    }

    // C/D layout: col = lane&15, row = quad*4 + reg
    #pragma unroll
    for (int mi = 0; mi < 4; mi++) {
        #pragma unroll
        for (int ni = 0; ni < 4; ni++) {
            const int col = col0 + wx * 64 + ni * 16 + l15;
            if (col < N) {
                const float bv = bias ? bias[col] : 0.f;
                #pragma unroll
                for (int rg = 0; rg < 4; rg++) {
                    const int row = row0 + wy * 64 + mi * 16 + quad * 4 + rg;
                    float t = acc[mi][ni][rg] * scale + bv;
                    if (leaky) t = t > 0.f ? t : 0.1f * t;
                    C[(size_t)row * N + col] = t;
                }
            }
        }
    }
}

// ---------------------------------------------------------------- casts
__global__ __launch_bounds__(256)
void cast_bf16_kernel(const float* __restrict__ in, __bf16* __restrict__ out, int n8) {
    int i = blockIdx.x * 256 + threadIdx.x;
    if (i >= n8) return;
    float4 a = ((const float4*)in)[2 * i];
    float4 b = ((const float4*)in)[2 * i + 1];
    bf16x8 v;
    v[0] = (__bf16)a.x; v[1] = (__bf16)a.y; v[2] = (__bf16)a.z; v[3] = (__bf16)a.w;
    v[4] = (__bf16)b.x; v[5] = (__bf16)b.y; v[6] = (__bf16)b.z; v[7] = (__bf16)b.w;
    ((bf16x8*)out)[i] = v;
}

// bn-apply + cast; channel = (j/L)%C
template<int C, int L>
__global__ __launch_bounds__(256)
void bn_apply_cast_kernel(const float* __restrict__ in, __bf16* __restrict__ out,
                          const float* __restrict__ SS, int n8) {
    int i = blockIdx.x * 256 + threadIdx.x;
    if (i >= n8) return;
    float4 a = ((const float4*)in)[2 * i];
    float4 b = ((const float4*)in)[2 * i + 1];
    float vv[8] = {a.x, a.y, a.z, a.w, b.x, b.y, b.z, b.w};
    const int j0 = i * 8;
    bf16x8 v;
    #pragma unroll
    for (int e = 0; e < 8; e++) {
        const int ch = ((j0 + e) / L) % C;
        v[e] = (__bf16)fmaf(vv[e], SS[ch], SS[C + ch]);
    }
    ((bf16x8*)out)[i] = v;
}

__global__ __launch_bounds__(256)
void bn_apply_c512_kernel(float* __restrict__ Y, const float* __restrict__ SS, int n4) {
    int i = blockIdx.x * 256 + threadIdx.x;
    if (i >= n4) return;
    float4 v = ((float4*)Y)[i];
    const int c = (i * 4) & 511;
    v.x = fmaf(v.x, SS[c + 0], SS[512 + c + 0]);
    v.y = fmaf(v.y, SS[c + 1], SS[512 + c + 1]);
    v.z = fmaf(v.z, SS[c + 2], SS[512 + c + 2]);
    v.w = fmaf(v.w, SS[c + 3], SS[512 + c + 3]);
    ((float4*)Y)[i] = v;
}

// in f32 [R,C] -> out bf16 [C,R]
__global__ __launch_bounds__(256)
void transpose_cast_kernel(const float* __restrict__ in, __bf16* __restrict__ out,
                           int R, int C) {
    __shared__ float t[32][33];
    const int c0 = blockIdx.x * 32, r0 = blockIdx.y * 32;
    const int cc = threadIdx.x & 31, rr = threadIdx.x >> 5;   // rr 0..7
    #pragma unroll
    for (int i = 0; i < 32; i += 8)
        t[rr + i][cc] = in[(size_t)(r0 + rr + i) * C + c0 + cc];
    __syncthreads();
    #pragma unroll
    for (int i = 0; i < 32; i += 8)
        out[(size_t)(c0 + rr + i) * R + r0 + cc] = (__bf16)t[cc][rr + i];
}

// ---------------------------------------------------------------- softmaxes
__global__ __launch_bounds__(256)
void softmax4k_kernel(float* __restrict__ P) {
    float* p = P + (size_t)blockIdx.x * 4096;
    float v[16];
    float mx = -INFINITY;
    #pragma unroll
    for (int i = 0; i < 16; i++) {
        v[i] = p[threadIdx.x + i * 256];
        mx = fmaxf(mx, v[i]);
    }
    mx = blockReduceMax256(mx);
    float s = 0.f;
    #pragma unroll
    for (int i = 0; i < 16; i++) { v[i] = __expf(v[i] - mx); s += v[i]; }
    s = blockReduceSum256(s);
    const float inv = 1.f / s;
    #pragma unroll
    for (int i = 0; i < 16; i++) p[threadIdx.x + i * 256] = v[i] * inv;
}

__global__ __launch_bounds__(256)
void softmax_fc_kernel(float* __restrict__ P) {
    float* p = P + (size_t)blockIdx.x * 32000;
    float mx = -INFINITY;
    for (int i = threadIdx.x; i < 32000; i += 256) mx = fmaxf(mx, p[i]);
    mx = blockReduceMax256(mx);
    float s = 0.f;
    for (int i = threadIdx.x; i < 32000; i += 256) {
        float e = __expf(p[i] - mx);
        p[i] = e; s += e;
    }
    s = blockReduceSum256(s);
    const float inv = 1.f / s;
    for (int i = threadIdx.x; i < 32000; i += 256) p[i] *= inv;
}

// ---------------------------------------------------------------- assemble s
__global__ __launch_bounds__(320)
void assemble_s_kernel(const int* __restrict__ X, const float* __restrict__ Emb,
                       const float* __restrict__ Cf, const float* __restrict__ Mo,
                       __bf16* __restrict__ S) {
    const int m = blockIdx.x;
    const int col = threadIdx.x * 4;
    float4 v;
    if (col < 256)      v = *(const float4*)(Emb + (size_t)X[m] * 256 + col);
    else if (col < 768) v = *(const float4*)(Cf + (size_t)m * 512 + (col - 256));
    else                v = *(const float4*)(Mo + (size_t)m * 512 + (col - 768));
    bf16x4 o;
    o[0] = (__bf16)v.x; o[1] = (__bf16)v.y; o[2] = (__bf16)v.z; o[3] = (__bf16)v.w;
    *(bf16x4*)(S + (size_t)m * 1280 + col) = o;
}

// ---------------------------------------------------------------- launch
extern "C" void kernel_launch(void* const* d_in, const int* in_sizes, int n_in,
                              void* d_out, int out_size, void* d_ws, size_t ws_size,
                              hipStream_t stream) {
    const int*   x    = (const int*)d_in[0];
    const int*   c    = (const int*)d_in[1];
    const float* emb  = (const float*)d_in[2];
    const float* w1 = (const float*)d_in[3],  *b1 = (const float*)d_in[4];
    const float* g1 = (const float*)d_in[5],  *be1 = (const float*)d_in[6];
    const float* w2 = (const float*)d_in[7],  *b2 = (const float*)d_in[8];
    const float* g2 = (const float*)d_in[9],  *be2 = (const float*)d_in[10];
    const float* w3 = (const float*)d_in[11], *b3 = (const float*)d_in[12];
    const float* g3 = (const float*)d_in[13], *be3 = (const float*)d_in[14];
    const float* w4 = (const float*)d_in[15], *b4 = (const float*)d_in[16];
    const float* g4 = (const float*)d_in[17], *be4 = (const float*)d_in[18];
    const float* w5 = (const float*)d_in[19], *b5 = (const float*)d_in[20];
    const float* g5 = (const float*)d_in[21], *be5 = (const float*)d_in[22];
    const float* fcW = (const float*)d_in[23], *fcb = (const float*)d_in[24];
    const float* memK = (const float*)d_in[25], *memV = (const float*)d_in[26];
    float* out = (float*)d_out;

    // ---------------- workspace layout (bytes; total 162,729,984) ----------
    char* W = (char*)d_ws;
    __bf16* fcWT_bf  = (__bf16*)(W + 0);          // 32000x1280  (81,920,000)
    __bf16* memK_bf  = (__bf16*)(W + 81920000);   // 4096x512    (4,194,304)
    __bf16* memVT_bf = (__bf16*)(W + 86114304);   // 512x4096    (4,194,304)
    __bf16* w5t      = (__bf16*)(W + 90308608);   // 512x3584    (3,670,016)
    __bf16* w4t      = (__bf16*)(W + 93978624);   // 256x1024    (524,288)
    __bf16* w3t      = (__bf16*)(W + 94502912);   // 128x512     (131,072)
    __bf16* w2t      = (__bf16*)(W + 94633984);   // 128x256     (65,536)
    __bf16* w1t      = (__bf16*)(W + 94699520);   // 128x512     (131,072)
    float*  SS       = (float*)(W + 94830592);    // 1024 f      (4,096)
    float2* part     = (float2*)(W + 94834688);   // 65536 f2    (524,288)
    // region P (34,340,864): Gt -> A2 -> A3 -> A4 -> A5 -> scores+attn
    char* P = W + 95358976;
    __bf16* Gt      = (__bf16*)P;                 // 1024*262*64 (34,340,864)
    __bf16* A2      = (__bf16*)P;                 // 63488x256   (32,505,856)
    __bf16* A3      = (__bf16*)P;                 // 30720x512   (31,457,280)
    __bf16* A4      = (__bf16*)P;                 // 14336x1024  (29,360,128)
    __bf16* A5      = (__bf16*)P;                 // 1024x3584   (7,340,032)
    float*  scores  = (float*)P;                  // 1024x4096   (16,777,216)
    __bf16* attn_bf = (__bf16*)(P + 16777216);    // 1024x4096   (8,388,608)
    // region Q (16,777,216): Y1 -> Y3 -> {cfeat, cfeat_bf, m_out, s_bf}
    char* Q = W + 129699840;
    float*  Y1       = (float*)Q;                 // 131072x32   (16,777,216)
    float*  Y3       = (float*)Q;                 // 30720x128   (15,728,640)
    float*  cfeat    = (float*)Q;                 // 1024x512    (2,097,152)
    __bf16* cfeat_bf = (__bf16*)(Q + 2097152);    // 1024x512    (1,048,576)
    float*  m_out    = (float*)(Q + 3145728);     // 1024x512    (2,097,152)
    __bf16* s_bf     = (__bf16*)(Q + 5242880);    // 1024x1280   (2,621,440)
    // region R (16,252,928): Y2 -> Y4
    char* R = W + 146477056;
    float*  Y2 = (float*)R;                       // 63488x64    (16,252,928)
    float*  Y4 = (float*)R;                       // 14336x256   (14,680,064)

    // ---------------- weight prep ----------------
    transpose_cast_kernel<<<dim3(1000, 40), 256, 0, stream>>>(fcW, fcWT_bf, 1280, 32000);
    transpose_cast_kernel<<<dim3(16, 128), 256, 0, stream>>>(memV, memVT_bf, 4096, 512);
    cast_bf16_kernel<<<1024, 256, 0, stream>>>(memK, memK_bf, 262144);
    wt_kernel<<<128, 256, 0, stream>>>(w1, w1t, 32, 64, 8);
    wt_kernel<<<128, 256, 0, stream>>>(w2, w2t, 64, 32, 8);
    wt_kernel<<<128, 256, 0, stream>>>(w3, w3t, 128, 64, 8);
    wt_kernel<<<256, 256, 0, stream>>>(w4, w4t, 256, 128, 8);
    wt_kernel<<<512, 256, 0, stream>>>(w5, w5t, 512, 256, 14);

    // ---------------- conv1: gather-transpose + strided-view GEMM ----------
    gather_tr_kernel<<<1024, 256, 0, stream>>>(c, emb, Gt);
    // Y1 [n*128+l, 32]; row l of block n reads Gt at n*16768 + l*128, len 512
    mfma_gemm_bt<<<dim3(1024, 1), 256, 0, stream>>>(Gt, w1t, b1, Y1,
        131072, 32, 512, 128, 16768LL, 1.0f, 1, 0);
    bn_stats_nlc_kernel<32, 127, 128, 512><<<512, 256, 0, stream>>>(Y1, part);
    bn_finalize_nlc_kernel<<<32, 64, 0, stream>>>(part, g1, be1, SS, 32, 512,
                                                  1.0f / (1024.f * 127.f));
    // ---------------- conv2 ----------------
    im2col_kernel<32, 127, 128, 62><<<7936, 256, 0, stream>>>(Y1, SS, A2);
    mfma_gemm_bt<<<dim3(496, 1), 256, 0, stream>>>(A2, w2t, b2, Y2,
        63488, 64, 256, 256, 32768LL, 1.0f, 1, 0);
    bn_stats_nlc_kernel<64, 62, 62, 256><<<256, 256, 0, stream>>>(Y2, part);
    bn_finalize_nlc_kernel<<<64, 64, 0, stream>>>(part, g2, be2, SS, 64, 256,
                                                  1.0f / (1024.f * 62.f));
    // ---------------- conv3 ----------------
    im2col_kernel<64, 62, 62, 30><<<7680, 256, 0, stream>>>(Y2, SS, A3);
    mfma_gemm_bt<<<dim3(240, 1), 256, 0, stream>>>(A3, w3t, b3, Y3,
        30720, 128, 512, 512, 65536LL, 1.0f, 1, 0);
    bn_stats_nlc_kernel<128, 30, 30, 256><<<256, 256, 0, stream>>>(Y3, part);
    bn_finalize_nlc_kernel<<<128, 64, 0, stream>>>(part, g3, be3, SS, 128, 256,
                                                   1.0f / (1024.f * 30.f));
    // ---------------- conv4 ----------------
    im2col_kernel<128, 30, 30, 14><<<7168, 256, 0, stream>>>(Y3, SS, A4);
    mfma_gemm_bt<<<dim3(112, 2), 256, 0, stream>>>(A4, w4t, b4, Y4,
        14336, 256, 1024, 1024, 131072LL, 1.0f, 1, 0);
    bn_stats_nlc_kernel<256, 14, 14, 256><<<256, 256, 0, stream>>>(Y4, part);
    bn_finalize_nlc_kernel<<<256, 64, 0, stream>>>(part, g4, be4, SS, 256, 256,
                                                   1.0f / (1024.f * 14.f));
    // ---------------- conv5 (full-reduce GEMM) ----------------
    // A5[n, l*256+ci] = bn4(Y4) : flat layouts coincide -> elementwise
    bn_apply_cast_kernel<256, 1><<<1792, 256, 0, stream>>>(Y4, A5, SS, 458752);
    mfma_gemm_bt<<<dim3(8, 4), 256, 0, stream>>>(A5, w5t, b5, cfeat,
        1024, 512, 3584, 3584, 458752LL, 1.0f, 1, 1);
    bn_stats_kernel<512, 1, 1><<<dim3(512, 1), 256, 0, stream>>>(cfeat, part);
    bn_finalize_kernel<<<512, 64, 0, stream>>>(part, g5, be5, SS, 512, 1,
                                               1.0f / 1024.f);
    bn_apply_c512_kernel<<<512, 256, 0, stream>>>(cfeat, SS, 131072);

    // ---------------- attention over memory ----------------
    cast_bf16_kernel<<<256, 256, 0, stream>>>(cfeat, cfeat_bf, 65536);
    mfma_gemm_bt<<<dim3(8, 32), 256, 0, stream>>>(cfeat_bf, memK_bf, nullptr, scores,
        1024, 4096, 512, 512, 65536LL, 0.04419417382415922f, 0, 1);
    softmax4k_kernel<<<1024, 256, 0, stream>>>(scores);
    cast_bf16_kernel<<<2048, 256, 0, stream>>>(scores, attn_bf, 524288);
    mfma_gemm_bt<<<dim3(8, 4), 256, 0, stream>>>(attn_bf, memVT_bf, nullptr, m_out,
        1024, 512, 4096, 4096, 524288LL, 1.0f, 0, 1);

    // ---------------- concat + fc + softmax ----------------
    assemble_s_kernel<<<1024, 320, 0, stream>>>(x, emb, cfeat, m_out, s_bf);
    mfma_gemm_bt<<<dim3(8, 250), 256, 0, stream>>>(s_bf, fcWT_bf, fcb, out,
        1024, 32000, 1280, 1280, 163840LL, 1.0f, 0, 1);
    softmax_fc_kernel<<<1024, 256, 0, stream>>>(out);
}

// Round 3
// 950.284 us; speedup vs baseline: 2.0272x; 1.1366x over previous
//
#include <hip/hip_runtime.h>
#include <hip/hip_bf16.h>
#include <math.h>

// Model: 5x (conv1d + bias + LeakyReLU(0.1) + BatchNorm(train-stats)) on
// embedded context, then content attention over a 4096-slot memory, concat
// [emb(x), cfeat, m_out] -> fc -> softmax over 32000 vocab.
//
// R3:
//  - NO materialized im2col anywhere: activations Y1..Y4 stored bf16 in
//    per-n padded [n][LSTR][C] layout; conv GEMM reads them as a strided
//    view (2-level row addressing). BN of layer i folds into conv i+1:
//    W' = W*sc[ci], bias' = b + sum(sh*W); pad rows hold -sh/sc so padding
//    contributes exactly 0 post-BN (matches reference zero-pad of the
//    normalized tensor).
//  - split-K GEMM for conv5 (S=8) and m_out (S=4): 32 blocks -> 256/128.
//  - GEMM LDS: data-quad rotation (slot (row,qp) holds K-quad
//    qp ^ ((row>>1)&3), pre-permuted global source, XOR'd read) ->
//    8-way bank conflict -> uniform 2-way (free), staging coalescing kept.
//  - softmax_fc online 2-pass (3 reads + 2 writes -> 2 reads + 1 write).

#define N_SAMP 1024

typedef __bf16 bf16x8 __attribute__((ext_vector_type(8)));
typedef __bf16 bf16x4 __attribute__((ext_vector_type(4)));
typedef float  f32x4  __attribute__((ext_vector_type(4)));

// ---------------------------------------------------------------- reductions
__device__ __forceinline__ float blockReduceMax256(float v) {
    __shared__ float sm[4];
    #pragma unroll
    for (int off = 32; off > 0; off >>= 1) v = fmaxf(v, __shfl_down(v, off, 64));
    if ((threadIdx.x & 63) == 0) sm[threadIdx.x >> 6] = v;
    __syncthreads();
    v = fmaxf(fmaxf(sm[0], sm[1]), fmaxf(sm[2], sm[3]));
    __syncthreads();
    return v;
}

__device__ __forceinline__ float blockReduceSum256(float v) {
    __shared__ float sm[4];
    #pragma unroll
    for (int off = 32; off > 0; off >>= 1) v += __shfl_down(v, off, 64);
    if ((threadIdx.x & 63) == 0) sm[threadIdx.x >> 6] = v;
    __syncthreads();
    v = sm[0] + sm[1] + sm[2] + sm[3];
    __syncthreads();
    return v;
}

// ------------------------------------------------------- conv1 input prep
// Gt[n, 2+li, ci] = Emb[c[n,ci]*256 + li], li in [0,256); rows 0,1 and
// 258..261 zero (left pad 2, right pad for l=127 tail). 262 rows/n.
__global__ __launch_bounds__(256)
void gather_tr_kernel(const int* __restrict__ Cidx, const float* __restrict__ Emb,
                      __bf16* __restrict__ Gt) {
    const int n = blockIdx.x;
    __shared__ int idx[64];
    __shared__ float t[64][65];
    if (threadIdx.x < 64) idx[threadIdx.x] = Cidx[n * 64 + threadIdx.x];
    __bf16* g = Gt + (size_t)n * (262 * 64);
    for (int i = threadIdx.x; i < 6 * 64; i += 256) {
        int r = i >> 6;
        int phys = (r < 2) ? r : r + 256;   // 0,1,258,259,260,261
        g[(size_t)phys * 64 + (i & 63)] = (__bf16)0.f;
    }
    for (int c0 = 0; c0 < 256; c0 += 64) {
        __syncthreads();
        for (int i = threadIdx.x; i < 4096; i += 256) {
            int ci = i >> 6, li = i & 63;
            t[ci][li] = Emb[(size_t)idx[ci] * 256 + c0 + li];
        }
        __syncthreads();
        for (int i = threadIdx.x; i < 4096; i += 256) {
            int li = i >> 6, ci = i & 63;
            g[(size_t)(2 + c0 + li) * 64 + ci] = (__bf16)t[ci][li];
        }
    }
}

// ------------------------------------------------- weight transform + BN fold
// W [CO, CI, KW] fp32 -> Wt [gridDim.x rows, K=KW*CI] bf16 with kidx=k*CI+ci,
// Wt = W*sc[ci]; bias'[co] = B[co] + sum_{ci,k} sh[ci]*W. SS==null -> identity.
__global__ __launch_bounds__(256)
void wt_fold_kernel(const float* __restrict__ W, const float* __restrict__ B,
                    const float* __restrict__ SS, __bf16* __restrict__ Wt,
                    float* __restrict__ bias, int CO, int CI, int KW) {
    const int co = blockIdx.x;
    const int K = CI * KW;
    float local = 0.f;
    if (co < CO) {
        for (int i = threadIdx.x; i < K; i += 256) {
            int k = i / CI, ci = i - k * CI;
            float w = W[((size_t)co * CI + ci) * KW + k];
            float sc = SS ? SS[ci] : 1.f;
            Wt[(size_t)co * K + i] = (__bf16)(w * sc);
            if (SS) local = fmaf(SS[CI + ci], w, local);
        }
    } else {
        for (int i = threadIdx.x; i < K; i += 256)
            Wt[(size_t)co * K + i] = (__bf16)0.f;
    }
    __shared__ float sm[4];
    #pragma unroll
    for (int off = 32; off > 0; off >>= 1) local += __shfl_down(local, off, 64);
    if ((threadIdx.x & 63) == 0) sm[threadIdx.x >> 6] = local;
    __syncthreads();
    if (threadIdx.x == 0 && co < CO)
        bias[co] = B[co] + sm[0] + sm[1] + sm[2] + sm[3];
}

// ------------------------------------------------- pad-row fill (post-stats)
// Pad rows hold p = -sh/sc so that p*sc + sh = 0 (zero post-BN contribution).
__global__ __launch_bounds__(256)
void padfill_kernel(__bf16* __restrict__ Y, const float* __restrict__ SS,
                    int C, int LSTR, int4 rows, int nrows) {
    const int n = blockIdx.x;
    const int rr[4] = {rows.x, rows.y, rows.z, rows.w};
    for (int i = threadIdx.x; i < nrows * C; i += 256) {
        int j = i / C, c = i - j * C;
        float p = -SS[C + c] / SS[c];
        Y[((size_t)n * LSTR + rr[j]) * C + c] = (__bf16)p;
    }
}

// ---------------------------------------------------------------- batchnorm
// stats over padded bf16 [n][LSTR][C], valid rows phys = 2+l, l<LOUT.
template<int C, int LOUT, int LSTR, int NB>
__global__ __launch_bounds__(256)
void bn_stats_bf_kernel(const __bf16* __restrict__ Y, float2* __restrict__ partial) {
    constexpr int RPT = 256 / C;
    constexpr int M = N_SAMP * LOUT;
    const int col = threadIdx.x & (C - 1);
    const int rofs = threadIdx.x / C;
    float s = 0.f, s2 = 0.f;
    for (int m = blockIdx.x * RPT + rofs; m < M; m += NB * RPT) {
        int n = m / LOUT, l = m - n * LOUT;
        float v = (float)Y[((size_t)n * LSTR + 2 + l) * C + col];
        s += v; s2 = fmaf(v, v, s2);
    }
    __shared__ float sm[256], sm2[256];
    sm[threadIdx.x] = s; sm2[threadIdx.x] = s2;
    __syncthreads();
    #pragma unroll
    for (int off = 128; off >= C; off >>= 1) {
        if (threadIdx.x < off) {
            sm[threadIdx.x] += sm[threadIdx.x + off];
            sm2[threadIdx.x] += sm2[threadIdx.x + off];
        }
        __syncthreads();
    }
    if (threadIdx.x < C)
        partial[(size_t)blockIdx.x * C + threadIdx.x] =
            make_float2(sm[threadIdx.x], sm2[threadIdx.x]);
}

// cfeat [1024][512] fp32 stats: block b sums rows 4b..4b+3 per col.
__global__ __launch_bounds__(256)
void bn_stats_cf_kernel(const float* __restrict__ Y, float2* __restrict__ partial) {
    const int n0 = blockIdx.x * 4;
    for (int c = threadIdx.x; c < 512; c += 256) {
        float s = 0.f, s2 = 0.f;
        #pragma unroll
        for (int r = 0; r < 4; r++) {
            float v = Y[(size_t)(n0 + r) * 512 + c];
            s += v; s2 = fmaf(v, v, s2);
        }
        partial[(size_t)blockIdx.x * 512 + c] = make_float2(s, s2);
    }
}

// partial [NB][C] -> SS[c]=scale, SS[C+c]=shift
__global__ __launch_bounds__(64)
void bn_finalize_kernel(const float2* __restrict__ partial,
                        const float* __restrict__ G, const float* __restrict__ Be,
                        float* __restrict__ SS, int C, int NB, float invCnt) {
    const int c = blockIdx.x;
    float s = 0.f, s2 = 0.f;
    for (int i = threadIdx.x; i < NB; i += 64) {
        float2 p = partial[(size_t)i * C + c];
        s += p.x; s2 += p.y;
    }
    #pragma unroll
    for (int off = 32; off > 0; off >>= 1) {
        s  += __shfl_down(s,  off, 64);
        s2 += __shfl_down(s2, off, 64);
    }
    if (threadIdx.x == 0) {
        double mu  = (double)s * invCnt;
        double var = (double)s2 * invCnt - mu * mu;
        float sc = (float)((double)G[c] / sqrt(var + 1e-5));
        SS[c] = sc;
        SS[C + c] = (float)((double)Be[c] - mu * sc);
    }
}

// ---------------------------------------------------------------- MFMA GEMM
// C = act(scale * A·B^T + bias[col]). A-row r of block bx at
// A + bx*ablk + (r>>rpbl)*lda2 + (r&mask)*lda (2-level strided view).
// C store: bx*(128>>rpbl)*ldc2 + (row>>rpbl)*ldc2 + (row&mask)*N + col,
// masked col<N; cdt: 0=f32, 1=bf16. Split-K via gridDim.z (ksplit, csplit).
// LDS: data-quad rotation -> 2-way (free) bank aliasing on ds_read_b128.
__device__ __forceinline__ void gld16(const __bf16* g, __bf16* l) {
    __builtin_amdgcn_global_load_lds(
        (const __attribute__((address_space(1))) unsigned int*)g,
        (__attribute__((address_space(3))) unsigned int*)l, 16, 0, 0);
}

__global__ __launch_bounds__(256)
void mfma_gemm_bt(const __bf16* __restrict__ A, const __bf16* __restrict__ B,
                  const float* __restrict__ bias, void* __restrict__ Cv,
                  int N, int K, int ksplit,
                  int lda, int lda2, int rpbl, long long ablk,
                  int ldc2, long long csplit,
                  float scale, int leaky, int swz, int cdt) {
    __shared__ __bf16 As[128 * 32];
    __shared__ __bf16 Bs[128 * 32];
    const int tid = threadIdx.x;
    int bx = blockIdx.x, by = blockIdx.y;
    if (swz) {
        const int gx = gridDim.x;
        const int G = gx * gridDim.y;
        const int bid = by * gx + bx;
        const int fid = (bid & 7) * (G >> 3) + (bid >> 3);
        bx = fid % gx; by = fid / gx;
    }
    const int col0 = by * 128;
    const int rpbm = (1 << rpbl) - 1;

    // staging: thread t -> LDS slot (row=t>>2, qp=t&3); global K-quad
    // kb = (qp ^ ((row>>1)&3)) (data-quad rotation; (t>>3)&3 == (row>>1)&3)
    const int r  = tid >> 2;
    const int kb = (((tid & 3) ^ ((tid >> 3) & 3))) * 8;
    const int r1 = r + 64;
    const __bf16* Ab = A + (size_t)bx * ablk;
    const __bf16* Ag0 = Ab + (size_t)(r  >> rpbl) * lda2 + (size_t)(r  & rpbm) * lda + kb;
    const __bf16* Ag1 = Ab + (size_t)(r1 >> rpbl) * lda2 + (size_t)(r1 & rpbm) * lda + kb;
    const __bf16* Bg0 = B + (size_t)(col0 + r ) * K + kb;
    const __bf16* Bg1 = B + (size_t)(col0 + r1) * K + kb;
    __bf16* Al0 = As + tid * 8;
    __bf16* Al1 = As + 2048 + tid * 8;
    __bf16* Bl0 = Bs + tid * 8;
    __bf16* Bl1 = Bs + 2048 + tid * 8;

    const int lane = tid & 63;
    const int wave = tid >> 6;
    const int wy = wave >> 1, wx = wave & 1;
    const int l15 = lane & 15, quad = lane >> 4;
    const int xq = (quad ^ ((l15 >> 1) & 3)) * 8;   // rotated read quad

    f32x4 acc[4][4] = {};

    const int k0s = blockIdx.z * ksplit;
    const int k0e = k0s + ksplit;
    for (int k0 = k0s; k0 < k0e; k0 += 32) {
        __syncthreads();
        gld16(Ag0 + k0, Al0);
        gld16(Ag1 + k0, Al1);
        gld16(Bg0 + k0, Bl0);
        gld16(Bg1 + k0, Bl1);
        __syncthreads();

        bf16x8 af[4], bfr[4];
        #pragma unroll
        for (int mi = 0; mi < 4; mi++)
            af[mi] = *(const bf16x8*)&As[(wy * 64 + mi * 16 + l15) * 32 + xq];
        #pragma unroll
        for (int ni = 0; ni < 4; ni++)
            bfr[ni] = *(const bf16x8*)&Bs[(wx * 64 + ni * 16 + l15) * 32 + xq];
        #pragma unroll
        for (int mi = 0; mi < 4; mi++)
            #pragma unroll
            for (int ni = 0; ni < 4; ni++)
                acc[mi][ni] = __builtin_amdgcn_mfma_f32_16x16x32_bf16(
                    af[mi], bfr[ni], acc[mi][ni], 0, 0, 0);
    }

    // C/D layout: col = lane&15, row = quad*4 + reg
    const long long cb = (long long)blockIdx.z * csplit
                       + (long long)bx * (long long)((128 >> rpbl) * ldc2);
    #pragma unroll
    for (int mi = 0; mi < 4; mi++) {
        #pragma unroll
        for (int ni = 0; ni < 4; ni++) {
            const int col = col0 + wx * 64 + ni * 16 + l15;
            if (col < N) {
                const float bv = bias ? bias[col] : 0.f;
                #pragma unroll
                for (int rg = 0; rg < 4; rg++) {
                    const int row = wy * 64 + mi * 16 + quad * 4 + rg;
                    const long long a = cb + (long long)(row >> rpbl) * ldc2
                                      + (long long)(row & rpbm) * N + col;
                    float t = acc[mi][ni][rg] * scale + bv;
                    if (leaky) t = t > 0.f ? t : 0.1f * t;
                    if (cdt) ((__bf16*)Cv)[a] = (__bf16)t;
                    else     ((float*)Cv)[a] = t;
                }
            }
        }
    }
}

// ---------------------------------------------------------------- split-K
__global__ __launch_bounds__(256)
void splitk_reduce_kernel(const float* __restrict__ P, float* __restrict__ out,
                          const float* __restrict__ bias, int S, int MN, int N,
                          int leaky) {
    int i = blockIdx.x * 256 + threadIdx.x;    // float4 index
    const int tot = MN >> 2;
    if (i >= tot) return;
    float ax = 0.f, ay = 0.f, az = 0.f, aw = 0.f;
    for (int s = 0; s < S; s++) {
        float4 p = ((const float4*)(P + (size_t)s * MN))[i];
        ax += p.x; ay += p.y; az += p.z; aw += p.w;
    }
    const int c0 = (i * 4) & (N - 1);
    float4 o;
    o.x = ax + (bias ? bias[c0 + 0] : 0.f);
    o.y = ay + (bias ? bias[c0 + 1] : 0.f);
    o.z = az + (bias ? bias[c0 + 2] : 0.f);
    o.w = aw + (bias ? bias[c0 + 3] : 0.f);
    if (leaky) {
        o.x = o.x > 0.f ? o.x : 0.1f * o.x;
        o.y = o.y > 0.f ? o.y : 0.1f * o.y;
        o.z = o.z > 0.f ? o.z : 0.1f * o.z;
        o.w = o.w > 0.f ? o.w : 0.1f * o.w;
    }
    ((float4*)out)[i] = o;
}

// ---------------------------------------------------------------- casts
__global__ __launch_bounds__(256)
void cast_bf16_kernel(const float* __restrict__ in, __bf16* __restrict__ out, int n8) {
    int i = blockIdx.x * 256 + threadIdx.x;
    if (i >= n8) return;
    float4 a = ((const float4*)in)[2 * i];
    float4 b = ((const float4*)in)[2 * i + 1];
    bf16x8 v;
    v[0] = (__bf16)a.x; v[1] = (__bf16)a.y; v[2] = (__bf16)a.z; v[3] = (__bf16)a.w;
    v[4] = (__bf16)b.x; v[5] = (__bf16)b.y; v[6] = (__bf16)b.z; v[7] = (__bf16)b.w;
    ((bf16x8*)out)[i] = v;
}

// bn-apply for cfeat: in-place fp32 + bf16 copy
__global__ __launch_bounds__(256)
void bn_apply_both_kernel(float* __restrict__ Y, __bf16* __restrict__ Yb,
                          const float* __restrict__ SS, int n4) {
    int i = blockIdx.x * 256 + threadIdx.x;
    if (i >= n4) return;
    float4 v = ((float4*)Y)[i];
    const int c = (i * 4) & 511;
    v.x = fmaf(v.x, SS[c + 0], SS[512 + c + 0]);
    v.y = fmaf(v.y, SS[c + 1], SS[512 + c + 1]);
    v.z = fmaf(v.z, SS[c + 2], SS[512 + c + 2]);
    v.w = fmaf(v.w, SS[c + 3], SS[512 + c + 3]);
    ((float4*)Y)[i] = v;
    bf16x4 o;
    o[0] = (__bf16)v.x; o[1] = (__bf16)v.y; o[2] = (__bf16)v.z; o[3] = (__bf16)v.w;
    ((bf16x4*)Yb)[i] = o;
}

// in f32 [R,C] -> out bf16 [C,R]
__global__ __launch_bounds__(256)
void transpose_cast_kernel(const float* __restrict__ in, __bf16* __restrict__ out,
                           int R, int C) {
    __shared__ float t[32][33];
    const int c0 = blockIdx.x * 32, r0 = blockIdx.y * 32;
    const int cc = threadIdx.x & 31, rr = threadIdx.x >> 5;   // rr 0..7
    #pragma unroll
    for (int i = 0; i < 32; i += 8)
        t[rr + i][cc] = in[(size_t)(r0 + rr + i) * C + c0 + cc];
    __syncthreads();
    #pragma unroll
    for (int i = 0; i < 32; i += 8)
        out[(size_t)(c0 + rr + i) * R + r0 + cc] = (__bf16)t[cc][rr + i];
}

// ---------------------------------------------------------------- softmaxes
__global__ __launch_bounds__(256)
void softmax4k_kernel(float* __restrict__ P) {
    float* p = P + (size_t)blockIdx.x * 4096;
    float v[16];
    float mx = -INFINITY;
    #pragma unroll
    for (int i = 0; i < 16; i++) {
        v[i] = p[threadIdx.x + i * 256];
        mx = fmaxf(mx, v[i]);
    }
    mx = blockReduceMax256(mx);
    float s = 0.f;
    #pragma unroll
    for (int i = 0; i < 16; i++) { v[i] = __expf(v[i] - mx); s += v[i]; }
    s = blockReduceSum256(s);
    const float inv = 1.f / s;
    #pragma unroll
    for (int i = 0; i < 16; i++) p[threadIdx.x + i * 256] = v[i] * inv;
}

// online 2-pass (was 3-pass)
__global__ __launch_bounds__(256)
void softmax_fc_kernel(float* __restrict__ P) {
    float* p = P + (size_t)blockIdx.x * 32000;
    float m = -INFINITY, s = 0.f;
    for (int i = threadIdx.x; i < 32000; i += 256) {
        float v = p[i];
        if (v > m) { s = s * __expf(m - v) + 1.f; m = v; }
        else       { s += __expf(v - m); }
    }
    const float M = blockReduceMax256(m);
    s *= __expf(m - M);
    const float S = blockReduceSum256(s);
    const float inv = 1.f / S;
    for (int i = threadIdx.x; i < 32000; i += 256)
        p[i] = __expf(p[i] - M) * inv;
}

// ---------------------------------------------------------------- assemble s
__global__ __launch_bounds__(320)
void assemble_s_kernel(const int* __restrict__ X, const float* __restrict__ Emb,
                       const float* __restrict__ Cf, const float* __restrict__ Mo,
                       __bf16* __restrict__ S) {
    const int m = blockIdx.x;
    const int col = threadIdx.x * 4;
    float4 v;
    if (col < 256)      v = *(const float4*)(Emb + (size_t)X[m] * 256 + col);
    else if (col < 768) v = *(const float4*)(Cf + (size_t)m * 512 + (col - 256));
    else                v = *(const float4*)(Mo + (size_t)m * 512 + (col - 768));
    bf16x4 o;
    o[0] = (__bf16)v.x; o[1] = (__bf16)v.y; o[2] = (__bf16)v.z; o[3] = (__bf16)v.w;
    *(bf16x4*)(S + (size_t)m * 1280 + col) = o;
}

// ---------------------------------------------------------------- launch
extern "C" void kernel_launch(void* const* d_in, const int* in_sizes, int n_in,
                              void* d_out, int out_size, void* d_ws, size_t ws_size,
                              hipStream_t stream) {
    const int*   x    = (const int*)d_in[0];
    const int*   c    = (const int*)d_in[1];
    const float* emb  = (const float*)d_in[2];
    const float* w1 = (const float*)d_in[3],  *b1 = (const float*)d_in[4];
    const float* g1 = (const float*)d_in[5],  *be1 = (const float*)d_in[6];
    const float* w2 = (const float*)d_in[7],  *b2 = (const float*)d_in[8];
    const float* g2 = (const float*)d_in[9],  *be2 = (const float*)d_in[10];
    const float* w3 = (const float*)d_in[11], *b3 = (const float*)d_in[12];
    const float* g3 = (const float*)d_in[13], *be3 = (const float*)d_in[14];
    const float* w4 = (const float*)d_in[15], *b4 = (const float*)d_in[16];
    const float* g4 = (const float*)d_in[17], *be4 = (const float*)d_in[18];
    const float* w5 = (const float*)d_in[19], *b5 = (const float*)d_in[20];
    const float* g5 = (const float*)d_in[21], *be5 = (const float*)d_in[22];
    const float* fcW = (const float*)d_in[23], *fcb = (const float*)d_in[24];
    const float* memK = (const float*)d_in[25], *memV = (const float*)d_in[26];
    float* out = (float*)d_out;

    // -------- workspace (bytes, all 256-aligned; total ~156.5 MB) --------
    char* W = (char*)d_ws;
    __bf16* fcWT_bf  = (__bf16*)(W + 0);            // 32000x1280 (81,920,000)
    __bf16* memK_bf  = (__bf16*)(W + 81920000);     // 4,194,304
    __bf16* memVT_bf = (__bf16*)(W + 86114304);     // 4,194,304
    __bf16* w5t      = (__bf16*)(W + 90308608);     // 512x3584  (3,670,016)
    __bf16* w4t      = (__bf16*)(W + 93978624);     // 256x1024  (524,288)
    __bf16* w3t      = (__bf16*)(W + 94502912);     // 128x512   (131,072)
    __bf16* w2t      = (__bf16*)(W + 94633984);     // 128x256   (65,536)
    __bf16* w1t      = (__bf16*)(W + 94699520);     // 128x512   (131,072)
    float*  SS       = (float*)(W + 94830592);      // 1024 f
    float*  BB       = (float*)(W + 94834688);      // 512 f
    float2* part     = (float2*)(W + 94836736);     // 131072 f2 (1,048,576)
    // YA: Y1 [1024][130][32] bf16 -> Y3 [1024][34][128] (+8K elem slack)
    __bf16* YA = (__bf16*)(W + 95885312);           // 8,929,280
    // YB: Y2 [1024][66][64] -> Y4 [1024][18][256] (+slack)
    __bf16* YB = (__bf16*)(W + 104814592);          // 9,453,568
    // P: Gt (34,340,864) -> conv5 partials (16MB) -> scores+attn+m_out parts
    char* P = W + 114268160;                        // 34,340,864
    __bf16* Gt      = (__bf16*)P;
    float*  Pc5     = (float*)P;                    // 8 x 1024x512 f32
    float*  scores  = (float*)P;                    // 1024x4096  (16,777,216)
    __bf16* attn_bf = (__bf16*)(P + 16777216);      // 8,388,608
    float*  Pmo     = (float*)(P + 25165824);       // 4 x 1024x512 (8,388,608)
    float*  cfeat    = (float*)(W + 148609024);     // 2,097,152
    __bf16* cfeat_bf = (__bf16*)(W + 150706176);    // 1,048,576
    float*  m_out    = (float*)(W + 151754752);     // 2,097,152
    __bf16* s_bf     = (__bf16*)(W + 153851904);    // 2,621,440

    __bf16* Y1 = YA; __bf16* Y3 = YA;
    __bf16* Y2 = YB; __bf16* Y4 = YB;

    // ---------------- weight prep ----------------
    transpose_cast_kernel<<<dim3(1000, 40), 256, 0, stream>>>(fcW, fcWT_bf, 1280, 32000);
    transpose_cast_kernel<<<dim3(16, 128), 256, 0, stream>>>(memV, memVT_bf, 4096, 512);
    cast_bf16_kernel<<<1024, 256, 0, stream>>>(memK, memK_bf, 262144);
    wt_fold_kernel<<<128, 256, 0, stream>>>(w1, b1, nullptr, w1t, BB, 32, 64, 8);
    gather_tr_kernel<<<1024, 256, 0, stream>>>(c, emb, Gt);

    // ---------------- conv1 ----------------
    // A = Gt strided view (lda=128, one n per 128-row block); out Y1 bf16
    mfma_gemm_bt<<<dim3(1024, 1), 256, 0, stream>>>(Gt, w1t, BB, Y1 + 64,
        32, 512, 512, 128, 0, 7, 16768LL, 4160, 0LL, 1.0f, 1, 0, 1);
    bn_stats_bf_kernel<32, 127, 130, 512><<<512, 256, 0, stream>>>(Y1, part);
    bn_finalize_kernel<<<32, 64, 0, stream>>>(part, g1, be1, SS, 32, 512,
                                              1.0f / (1024.f * 127.f));
    padfill_kernel<<<1024, 256, 0, stream>>>(Y1, SS, 32, 130,
                                             make_int4(0, 1, 129, 0), 3);
    wt_fold_kernel<<<128, 256, 0, stream>>>(w2, b2, SS, w2t, BB, 64, 32, 8);

    // ---------------- conv2 ----------------
    mfma_gemm_bt<<<dim3(512, 1), 256, 0, stream>>>(Y1, w2t, BB, Y2 + 128,
        64, 256, 256, 64, 4160, 6, 8320LL, 4224, 0LL, 1.0f, 1, 0, 1);
    bn_stats_bf_kernel<64, 62, 66, 256><<<256, 256, 0, stream>>>(Y2, part);
    bn_finalize_kernel<<<64, 64, 0, stream>>>(part, g2, be2, SS, 64, 256,
                                              1.0f / (1024.f * 62.f));
    padfill_kernel<<<1024, 256, 0, stream>>>(Y2, SS, 64, 66,
                                             make_int4(0, 1, 64, 65), 4);
    wt_fold_kernel<<<128, 256, 0, stream>>>(w3, b3, SS, w3t, BB, 128, 64, 8);

    // ---------------- conv3 ----------------
    mfma_gemm_bt<<<dim3(256, 1), 256, 0, stream>>>(Y2, w3t, BB, Y3 + 256,
        128, 512, 512, 128, 4224, 5, 16896LL, 4352, 0LL, 1.0f, 1, 0, 1);
    bn_stats_bf_kernel<128, 30, 34, 256><<<256, 256, 0, stream>>>(Y3, part);
    bn_finalize_kernel<<<128, 64, 0, stream>>>(part, g3, be3, SS, 128, 256,
                                               1.0f / (1024.f * 30.f));
    padfill_kernel<<<1024, 256, 0, stream>>>(Y3, SS, 128, 34,
                                             make_int4(0, 1, 32, 33), 4);
    wt_fold_kernel<<<256, 256, 0, stream>>>(w4, b4, SS, w4t, BB, 256, 128, 8);

    // ---------------- conv4 ----------------
    mfma_gemm_bt<<<dim3(128, 2), 256, 0, stream>>>(Y3, w4t, BB, Y4 + 512,
        256, 1024, 1024, 256, 4352, 4, 34816LL, 4608, 0LL, 1.0f, 1, 0, 1);
    bn_stats_bf_kernel<256, 14, 18, 256><<<256, 256, 0, stream>>>(Y4, part);
    bn_finalize_kernel<<<256, 64, 0, stream>>>(part, g4, be4, SS, 256, 256,
                                               1.0f / (1024.f * 14.f));
    wt_fold_kernel<<<512, 256, 0, stream>>>(w5, b5, SS, w5t, BB, 512, 256, 14);
    // (no padfill: conv5 reads only valid rows phys 2..15)

    // ---------------- conv5 (split-K 8) ----------------
    mfma_gemm_bt<<<dim3(8, 4, 8), 256, 0, stream>>>(Y4 + 512, w5t, nullptr, Pc5,
        512, 3584, 448, 4608, 0, 7, 589824LL, 65536, 524288LL, 1.0f, 0, 0, 0);
    splitk_reduce_kernel<<<512, 256, 0, stream>>>(Pc5, cfeat, BB, 8, 524288, 512, 1);
    bn_stats_cf_kernel<<<256, 256, 0, stream>>>(cfeat, part);
    bn_finalize_kernel<<<512, 64, 0, stream>>>(part, g5, be5, SS, 512, 256,
                                               1.0f / 1024.f);
    bn_apply_both_kernel<<<512, 256, 0, stream>>>(cfeat, cfeat_bf, SS, 131072);

    // ---------------- attention over memory ----------------
    mfma_gemm_bt<<<dim3(8, 32), 256, 0, stream>>>(cfeat_bf, memK_bf, nullptr, scores,
        4096, 512, 512, 512, 0, 7, 65536LL, 524288, 0LL,
        0.04419417382415922f, 0, 1, 0);
    softmax4k_kernel<<<1024, 256, 0, stream>>>(scores);
    cast_bf16_kernel<<<2048, 256, 0, stream>>>(scores, attn_bf, 524288);
    mfma_gemm_bt<<<dim3(8, 4, 4), 256, 0, stream>>>(attn_bf, memVT_bf, nullptr, Pmo,
        512, 4096, 1024, 4096, 0, 7, 524288LL, 65536, 524288LL, 1.0f, 0, 0, 0);
    splitk_reduce_kernel<<<512, 256, 0, stream>>>(Pmo, m_out, nullptr, 4, 524288, 512, 0);

    // ---------------- concat + fc + softmax ----------------
    assemble_s_kernel<<<1024, 320, 0, stream>>>(x, emb, cfeat, m_out, s_bf);
    mfma_gemm_bt<<<dim3(8, 250), 256, 0, stream>>>(s_bf, fcWT_bf, fcb, out,
        32000, 1280, 1280, 1280, 0, 7, 163840LL, 4096000, 0LL, 1.0f, 0, 1, 0);
    softmax_fc_kernel<<<1024, 256, 0, stream>>>(out);
}

// Round 4
// 933.199 us; speedup vs baseline: 2.0643x; 1.0183x over previous
//
#include <hip/hip_runtime.h>
#include <hip/hip_bf16.h>
#include <math.h>

// Model: 5x (conv1d + bias + LeakyReLU(0.1) + BatchNorm(train-stats)) on
// embedded context, then content attention over a 4096-slot memory, concat
// [emb(x), cfeat, m_out] -> fc -> softmax over 32000 vocab.
//
// R3: convs as strided-view bf16 MFMA GEMMs, BN folded into next conv's
//     weights, split-K for conv5/m_out, LDS data-quad rotation, online
//     softmax_fc.
// R4: fc GEMM moved to a 256x256/BK=64 8-wave deep-pipelined kernel
//     (mfma_gemm256_bt): double-buffered 128KiB LDS, counted vmcnt(8) via
//     inline asm + raw s_barrier (no drain in the main loop), quadrant
//     sub-phases with s_setprio around MFMA clusters, 3-bit XOR data
//     rotation for conflict-free ds_read_b128, bijective XCD block remap.
//     Race-safety is tile-granular: stage(t+1)->buf[x^1] only after the
//     barrier that ends all reads of buf[x^1] (prev iteration), and
//     vmcnt(8)+barrier before any ds_read of buf[x].

#define N_SAMP 1024

typedef __bf16 bf16x8 __attribute__((ext_vector_type(8)));
typedef __bf16 bf16x4 __attribute__((ext_vector_type(4)));
typedef float  f32x4  __attribute__((ext_vector_type(4)));

// ---------------------------------------------------------------- reductions
__device__ __forceinline__ float blockReduceMax256(float v) {
    __shared__ float sm[4];
    #pragma unroll
    for (int off = 32; off > 0; off >>= 1) v = fmaxf(v, __shfl_down(v, off, 64));
    if ((threadIdx.x & 63) == 0) sm[threadIdx.x >> 6] = v;
    __syncthreads();
    v = fmaxf(fmaxf(sm[0], sm[1]), fmaxf(sm[2], sm[3]));
    __syncthreads();
    return v;
}

__device__ __forceinline__ float blockReduceSum256(float v) {
    __shared__ float sm[4];
    #pragma unroll
    for (int off = 32; off > 0; off >>= 1) v += __shfl_down(v, off, 64);
    if ((threadIdx.x & 63) == 0) sm[threadIdx.x >> 6] = v;
    __syncthreads();
    v = sm[0] + sm[1] + sm[2] + sm[3];
    __syncthreads();
    return v;
}

// ------------------------------------------------------- conv1 input prep
__global__ __launch_bounds__(256)
void gather_tr_kernel(const int* __restrict__ Cidx, const float* __restrict__ Emb,
                      __bf16* __restrict__ Gt) {
    const int n = blockIdx.x;
    __shared__ int idx[64];
    __shared__ float t[64][65];
    if (threadIdx.x < 64) idx[threadIdx.x] = Cidx[n * 64 + threadIdx.x];
    __bf16* g = Gt + (size_t)n * (262 * 64);
    for (int i = threadIdx.x; i < 6 * 64; i += 256) {
        int r = i >> 6;
        int phys = (r < 2) ? r : r + 256;   // 0,1,258,259,260,261
        g[(size_t)phys * 64 + (i & 63)] = (__bf16)0.f;
    }
    for (int c0 = 0; c0 < 256; c0 += 64) {
        __syncthreads();
        for (int i = threadIdx.x; i < 4096; i += 256) {
            int ci = i >> 6, li = i & 63;
            t[ci][li] = Emb[(size_t)idx[ci] * 256 + c0 + li];
        }
        __syncthreads();
        for (int i = threadIdx.x; i < 4096; i += 256) {
            int li = i >> 6, ci = i & 63;
            g[(size_t)(2 + c0 + li) * 64 + ci] = (__bf16)t[ci][li];
        }
    }
}

// ------------------------------------------------- weight transform + BN fold
__global__ __launch_bounds__(256)
void wt_fold_kernel(const float* __restrict__ W, const float* __restrict__ B,
                    const float* __restrict__ SS, __bf16* __restrict__ Wt,
                    float* __restrict__ bias, int CO, int CI, int KW) {
    const int co = blockIdx.x;
    const int K = CI * KW;
    float local = 0.f;
    if (co < CO) {
        for (int i = threadIdx.x; i < K; i += 256) {
            int k = i / CI, ci = i - k * CI;
            float w = W[((size_t)co * CI + ci) * KW + k];
            float sc = SS ? SS[ci] : 1.f;
            Wt[(size_t)co * K + i] = (__bf16)(w * sc);
            if (SS) local = fmaf(SS[CI + ci], w, local);
        }
    } else {
        for (int i = threadIdx.x; i < K; i += 256)
            Wt[(size_t)co * K + i] = (__bf16)0.f;
    }
    __shared__ float sm[4];
    #pragma unroll
    for (int off = 32; off > 0; off >>= 1) local += __shfl_down(local, off, 64);
    if ((threadIdx.x & 63) == 0) sm[threadIdx.x >> 6] = local;
    __syncthreads();
    if (threadIdx.x == 0 && co < CO)
        bias[co] = B[co] + sm[0] + sm[1] + sm[2] + sm[3];
}

// ------------------------------------------------- pad-row fill (post-stats)
__global__ __launch_bounds__(256)
void padfill_kernel(__bf16* __restrict__ Y, const float* __restrict__ SS,
                    int C, int LSTR, int4 rows, int nrows) {
    const int n = blockIdx.x;
    const int rr[4] = {rows.x, rows.y, rows.z, rows.w};
    for (int i = threadIdx.x; i < nrows * C; i += 256) {
        int j = i / C, c = i - j * C;
        float p = -SS[C + c] / SS[c];
        Y[((size_t)n * LSTR + rr[j]) * C + c] = (__bf16)p;
    }
}

// ---------------------------------------------------------------- batchnorm
template<int C, int LOUT, int LSTR, int NB>
__global__ __launch_bounds__(256)
void bn_stats_bf_kernel(const __bf16* __restrict__ Y, float2* __restrict__ partial) {
    constexpr int RPT = 256 / C;
    constexpr int M = N_SAMP * LOUT;
    const int col = threadIdx.x & (C - 1);
    const int rofs = threadIdx.x / C;
    float s = 0.f, s2 = 0.f;
    for (int m = blockIdx.x * RPT + rofs; m < M; m += NB * RPT) {
        int n = m / LOUT, l = m - n * LOUT;
        float v = (float)Y[((size_t)n * LSTR + 2 + l) * C + col];
        s += v; s2 = fmaf(v, v, s2);
    }
    __shared__ float sm[256], sm2[256];
    sm[threadIdx.x] = s; sm2[threadIdx.x] = s2;
    __syncthreads();
    #pragma unroll
    for (int off = 128; off >= C; off >>= 1) {
        if (threadIdx.x < off) {
            sm[threadIdx.x] += sm[threadIdx.x + off];
            sm2[threadIdx.x] += sm2[threadIdx.x + off];
        }
        __syncthreads();
    }
    if (threadIdx.x < C)
        partial[(size_t)blockIdx.x * C + threadIdx.x] =
            make_float2(sm[threadIdx.x], sm2[threadIdx.x]);
}

__global__ __launch_bounds__(256)
void bn_stats_cf_kernel(const float* __restrict__ Y, float2* __restrict__ partial) {
    const int n0 = blockIdx.x * 4;
    for (int c = threadIdx.x; c < 512; c += 256) {
        float s = 0.f, s2 = 0.f;
        #pragma unroll
        for (int r = 0; r < 4; r++) {
            float v = Y[(size_t)(n0 + r) * 512 + c];
            s += v; s2 = fmaf(v, v, s2);
        }
        partial[(size_t)blockIdx.x * 512 + c] = make_float2(s, s2);
    }
}

__global__ __launch_bounds__(64)
void bn_finalize_kernel(const float2* __restrict__ partial,
                        const float* __restrict__ G, const float* __restrict__ Be,
                        float* __restrict__ SS, int C, int NB, float invCnt) {
    const int c = blockIdx.x;
    float s = 0.f, s2 = 0.f;
    for (int i = threadIdx.x; i < NB; i += 64) {
        float2 p = partial[(size_t)i * C + c];
        s += p.x; s2 += p.y;
    }
    #pragma unroll
    for (int off = 32; off > 0; off >>= 1) {
        s  += __shfl_down(s,  off, 64);
        s2 += __shfl_down(s2, off, 64);
    }
    if (threadIdx.x == 0) {
        double mu  = (double)s * invCnt;
        double var = (double)s2 * invCnt - mu * mu;
        float sc = (float)((double)G[c] / sqrt(var + 1e-5));
        SS[c] = sc;
        SS[C + c] = (float)((double)Be[c] - mu * sc);
    }
}

// ---------------------------------------------------------------- MFMA GEMM
__device__ __forceinline__ void gld16(const __bf16* g, __bf16* l) {
    __builtin_amdgcn_global_load_lds(
        (const __attribute__((address_space(1))) unsigned int*)g,
        (__attribute__((address_space(3))) unsigned int*)l, 16, 0, 0);
}

// 128x128 / BK=32 general kernel (strided-view A, split-K, masked cols)
__global__ __launch_bounds__(256)
void mfma_gemm_bt(const __bf16* __restrict__ A, const __bf16* __restrict__ B,
                  const float* __restrict__ bias, void* __restrict__ Cv,
                  int N, int K, int ksplit,
                  int lda, int lda2, int rpbl, long long ablk,
                  int ldc2, long long csplit,
                  float scale, int leaky, int swz, int cdt) {
    __shared__ __bf16 As[128 * 32];
    __shared__ __bf16 Bs[128 * 32];
    const int tid = threadIdx.x;
    int bx = blockIdx.x, by = blockIdx.y;
    if (swz) {
        const int gx = gridDim.x;
        const int G = gx * gridDim.y;
        const int bid = by * gx + bx;
        const int fid = (bid & 7) * (G >> 3) + (bid >> 3);
        bx = fid % gx; by = fid / gx;
    }
    const int col0 = by * 128;
    const int rpbm = (1 << rpbl) - 1;

    const int r  = tid >> 2;
    const int kb = (((tid & 3) ^ ((tid >> 3) & 3))) * 8;
    const int r1 = r + 64;
    const __bf16* Ab = A + (size_t)bx * ablk;
    const __bf16* Ag0 = Ab + (size_t)(r  >> rpbl) * lda2 + (size_t)(r  & rpbm) * lda + kb;
    const __bf16* Ag1 = Ab + (size_t)(r1 >> rpbl) * lda2 + (size_t)(r1 & rpbm) * lda + kb;
    const __bf16* Bg0 = B + (size_t)(col0 + r ) * K + kb;
    const __bf16* Bg1 = B + (size_t)(col0 + r1) * K + kb;
    __bf16* Al0 = As + tid * 8;
    __bf16* Al1 = As + 2048 + tid * 8;
    __bf16* Bl0 = Bs + tid * 8;
    __bf16* Bl1 = Bs + 2048 + tid * 8;

    const int lane = tid & 63;
    const int wave = tid >> 6;
    const int wy = wave >> 1, wx = wave & 1;
    const int l15 = lane & 15, quad = lane >> 4;
    const int xq = (quad ^ ((l15 >> 1) & 3)) * 8;

    f32x4 acc[4][4] = {};

    const int k0s = blockIdx.z * ksplit;
    const int k0e = k0s + ksplit;
    for (int k0 = k0s; k0 < k0e; k0 += 32) {
        __syncthreads();
        gld16(Ag0 + k0, Al0);
        gld16(Ag1 + k0, Al1);
        gld16(Bg0 + k0, Bl0);
        gld16(Bg1 + k0, Bl1);
        __syncthreads();

        bf16x8 af[4], bfr[4];
        #pragma unroll
        for (int mi = 0; mi < 4; mi++)
            af[mi] = *(const bf16x8*)&As[(wy * 64 + mi * 16 + l15) * 32 + xq];
        #pragma unroll
        for (int ni = 0; ni < 4; ni++)
            bfr[ni] = *(const bf16x8*)&Bs[(wx * 64 + ni * 16 + l15) * 32 + xq];
        #pragma unroll
        for (int mi = 0; mi < 4; mi++)
            #pragma unroll
            for (int ni = 0; ni < 4; ni++)
                acc[mi][ni] = __builtin_amdgcn_mfma_f32_16x16x32_bf16(
                    af[mi], bfr[ni], acc[mi][ni], 0, 0, 0);
    }

    const long long cb = (long long)blockIdx.z * csplit
                       + (long long)bx * (long long)((128 >> rpbl) * ldc2);
    #pragma unroll
    for (int mi = 0; mi < 4; mi++) {
        #pragma unroll
        for (int ni = 0; ni < 4; ni++) {
            const int col = col0 + wx * 64 + ni * 16 + l15;
            if (col < N) {
                const float bv = bias ? bias[col] : 0.f;
                #pragma unroll
                for (int rg = 0; rg < 4; rg++) {
                    const int row = wy * 64 + mi * 16 + quad * 4 + rg;
                    const long long a = cb + (long long)(row >> rpbl) * ldc2
                                      + (long long)(row & rpbm) * N + col;
                    float t = acc[mi][ni][rg] * scale + bv;
                    if (leaky) t = t > 0.f ? t : 0.1f * t;
                    if (cdt) ((__bf16*)Cv)[a] = (__bf16)t;
                    else     ((float*)Cv)[a] = t;
                }
            }
        }
    }
}

// ---------------- 256x256 / BK=64 / 8-wave deep-pipelined GEMM -------------
// Requires M%256==0, N%256==0, K%64==0, K>=128. C = A·B^T + bias (fp32 out).
#define SBAR() do { __builtin_amdgcn_sched_barrier(0); \
                    __builtin_amdgcn_s_barrier(); \
                    __builtin_amdgcn_sched_barrier(0); } while (0)

#define LDA256(mb) do { \
    _Pragma("unroll") \
    for (int m_ = 0; m_ < 4; m_++) \
        _Pragma("unroll") \
        for (int k_ = 0; k_ < 2; k_++) \
            afr[mb][m_][k_] = *(const bf16x8*)&Asl[((mb) * 64 + m_ * 16) * 64 + \
                ((((k_) << 2) + quad) ^ rotA) * 8]; \
} while (0)

#define LDB256(nb) do { \
    _Pragma("unroll") \
    for (int n_ = 0; n_ < 2; n_++) \
        _Pragma("unroll") \
        for (int k_ = 0; k_ < 2; k_++) \
            bfr[nb][n_][k_] = *(const bf16x8*)&Bsl[((nb) * 32 + n_ * 16) * 64 + \
                ((((k_) << 2) + quad) ^ rotB) * 8]; \
} while (0)

#define MM256(mb, nb) do { \
    _Pragma("unroll") \
    for (int m_ = 0; m_ < 4; m_++) \
        _Pragma("unroll") \
        for (int n_ = 0; n_ < 2; n_++) \
            _Pragma("unroll") \
            for (int k_ = 0; k_ < 2; k_++) \
                acc[(mb) * 4 + m_][(nb) * 2 + n_] = \
                    __builtin_amdgcn_mfma_f32_16x16x32_bf16( \
                        afr[mb][m_][k_], bfr[nb][n_][k_], \
                        acc[(mb) * 4 + m_][(nb) * 2 + n_], 0, 0, 0); \
} while (0)

#define STG256(ko, bb) do { \
    const size_t ko_ = (size_t)(ko); \
    gld16(Ab + ko_,            AldsB + (bb) * 16384); \
    gld16(Ab + ko_ +     giK,  AldsB + (bb) * 16384 + 4096); \
    gld16(Ab + ko_ + 2 * giK,  AldsB + (bb) * 16384 + 8192); \
    gld16(Ab + ko_ + 3 * giK,  AldsB + (bb) * 16384 + 12288); \
    gld16(Bb + ko_,            BldsB + (bb) * 16384); \
    gld16(Bb + ko_ +     giK,  BldsB + (bb) * 16384 + 4096); \
    gld16(Bb + ko_ + 2 * giK,  BldsB + (bb) * 16384 + 8192); \
    gld16(Bb + ko_ + 3 * giK,  BldsB + (bb) * 16384 + 12288); \
} while (0)

__global__ __launch_bounds__(512, 2)
void mfma_gemm256_bt(const __bf16* __restrict__ A, const __bf16* __restrict__ B,
                     const float* __restrict__ bias, float* __restrict__ C,
                     int M, int N, int K, int nwg) {
    __shared__ __bf16 As2[2 * 16384];
    __shared__ __bf16 Bs2[2 * 16384];
    const int tid = threadIdx.x;

    // bijective XCD-chunked remap (m204)
    const int bid = blockIdx.x;
    const int q8 = nwg >> 3, r8 = nwg & 7;
    const int xcd = bid & 7, o8 = bid >> 3;
    const int fid = (xcd < r8 ? xcd * (q8 + 1) : r8 * (q8 + 1) + (xcd - r8) * q8) + o8;
    const int gx = M >> 8;
    const int bx = fid % gx, by = fid / gx;
    const int row0 = bx << 8, col0 = by << 8;

    const int lane = tid & 63;
    const int wave = tid >> 6;
    const int wr = wave >> 2, wc = wave & 3;   // 2 (M) x 4 (N)
    const int l15 = lane & 15, quad = lane >> 4;

    // staging: thread -> (row = i*64 + tid>>3, slot = tid&7); LDS[row][s]
    // holds global k-quad s ^ (row&7)  (3-bit data rotation)
    const int rloc = tid >> 3;
    const int sq   = tid & 7;
    const int ksel = (sq ^ (rloc & 7)) << 3;
    const __bf16* Ab = A + (size_t)(row0 + rloc) * K + ksel;
    const __bf16* Bb = B + (size_t)(col0 + rloc) * K + ksel;
    __bf16* AldsB = As2 + tid * 8;
    __bf16* BldsB = Bs2 + tid * 8;
    const size_t giK = (size_t)64 * K;

    const int arow = wr * 128 + l15;
    const int brow = wc * 64 + l15;
    const int rotA = arow & 7, rotB = brow & 7;

    f32x4 acc[8][4] = {};
    bf16x8 afr[2][4][2];   // [mi-bank][m][kk]
    bf16x8 bfr[2][2][2];   // [ni-bank][n][kk]

    const int NT = K >> 6;
    STG256(0, 0);

    for (int t = 0; t < NT; ++t) {
        const int cb = t & 1;
        if (t + 1 < NT) {
            STG256((size_t)(t + 1) * 64, cb ^ 1);
            asm volatile("s_waitcnt vmcnt(8)" ::: "memory");
        } else {
            asm volatile("s_waitcnt vmcnt(0)" ::: "memory");
        }
        SBAR();                               // tile t resident everywhere

        const __bf16* Asl = As2 + cb * 16384 + arow * 64;
        const __bf16* Bsl = Bs2 + cb * 16384 + brow * 64;

        LDA256(0);                            // af_lo (8 reads)
        LDB256(0);                            // bf_lo (4 reads)
        SBAR();
        LDB256(1);                            // bf_hi in flight over MM(0,0)
        __builtin_amdgcn_s_setprio(1);
        MM256(0, 0);
        __builtin_amdgcn_s_setprio(0);
        SBAR();
        LDA256(1);                            // af_hi in flight over MM(0,1)
        __builtin_amdgcn_s_setprio(1);
        MM256(0, 1);
        __builtin_amdgcn_s_setprio(0);
        SBAR();
        __builtin_amdgcn_s_setprio(1);
        MM256(1, 0);
        __builtin_amdgcn_s_setprio(0);
        SBAR();
        __builtin_amdgcn_s_setprio(1);
        MM256(1, 1);
        __builtin_amdgcn_s_setprio(0);
        SBAR();                               // ends all reads of buf[cb]
    }

    #pragma unroll
    for (int mi = 0; mi < 8; mi++) {
        #pragma unroll
        for (int ni = 0; ni < 4; ni++) {
            const int colv = col0 + wc * 64 + ni * 16 + l15;
            const float bv = bias ? bias[colv] : 0.f;
            #pragma unroll
            for (int rg = 0; rg < 4; rg++) {
                const int row = row0 + wr * 128 + mi * 16 + quad * 4 + rg;
                C[(size_t)row * N + colv] = acc[mi][ni][rg] + bv;
            }
        }
    }
}

// ---------------------------------------------------------------- split-K
__global__ __launch_bounds__(256)
void splitk_reduce_kernel(const float* __restrict__ P, float* __restrict__ out,
                          const float* __restrict__ bias, int S, int MN, int N,
                          int leaky) {
    int i = blockIdx.x * 256 + threadIdx.x;
    const int tot = MN >> 2;
    if (i >= tot) return;
    float ax = 0.f, ay = 0.f, az = 0.f, aw = 0.f;
    for (int s = 0; s < S; s++) {
        float4 p = ((const float4*)(P + (size_t)s * MN))[i];
        ax += p.x; ay += p.y; az += p.z; aw += p.w;
    }
    const int c0 = (i * 4) & (N - 1);
    float4 o;
    o.x = ax + (bias ? bias[c0 + 0] : 0.f);
    o.y = ay + (bias ? bias[c0 + 1] : 0.f);
    o.z = az + (bias ? bias[c0 + 2] : 0.f);
    o.w = aw + (bias ? bias[c0 + 3] : 0.f);
    if (leaky) {
        o.x = o.x > 0.f ? o.x : 0.1f * o.x;
        o.y = o.y > 0.f ? o.y : 0.1f * o.y;
        o.z = o.z > 0.f ? o.z : 0.1f * o.z;
        o.w = o.w > 0.f ? o.w : 0.1f * o.w;
    }
    ((float4*)out)[i] = o;
}

// ---------------------------------------------------------------- casts
__global__ __launch_bounds__(256)
void cast_bf16_kernel(const float* __restrict__ in, __bf16* __restrict__ out, int n8) {
    int i = blockIdx.x * 256 + threadIdx.x;
    if (i >= n8) return;
    float4 a = ((const float4*)in)[2 * i];
    float4 b = ((const float4*)in)[2 * i + 1];
    bf16x8 v;
    v[0] = (__bf16)a.x; v[1] = (__bf16)a.y; v[2] = (__bf16)a.z; v[3] = (__bf16)a.w;
    v[4] = (__bf16)b.x; v[5] = (__bf16)b.y; v[6] = (__bf16)b.z; v[7] = (__bf16)b.w;
    ((bf16x8*)out)[i] = v;
}

__global__ __launch_bounds__(256)
void bn_apply_both_kernel(float* __restrict__ Y, __bf16* __restrict__ Yb,
                          const float* __restrict__ SS, int n4) {
    int i = blockIdx.x * 256 + threadIdx.x;
    if (i >= n4) return;
    float4 v = ((float4*)Y)[i];
    const int c = (i * 4) & 511;
    v.x = fmaf(v.x, SS[c + 0], SS[512 + c + 0]);
    v.y = fmaf(v.y, SS[c + 1], SS[512 + c + 1]);
    v.z = fmaf(v.z, SS[c + 2], SS[512 + c + 2]);
    v.w = fmaf(v.w, SS[c + 3], SS[512 + c + 3]);
    ((float4*)Y)[i] = v;
    bf16x4 o;
    o[0] = (__bf16)v.x; o[1] = (__bf16)v.y; o[2] = (__bf16)v.z; o[3] = (__bf16)v.w;
    ((bf16x4*)Yb)[i] = o;
}

__global__ __launch_bounds__(256)
void transpose_cast_kernel(const float* __restrict__ in, __bf16* __restrict__ out,
                           int R, int C) {
    __shared__ float t[32][33];
    const int c0 = blockIdx.x * 32, r0 = blockIdx.y * 32;
    const int cc = threadIdx.x & 31, rr = threadIdx.x >> 5;   // rr 0..7
    #pragma unroll
    for (int i = 0; i < 32; i += 8)
        t[rr + i][cc] = in[(size_t)(r0 + rr + i) * C + c0 + cc];
    __syncthreads();
    #pragma unroll
    for (int i = 0; i < 32; i += 8)
        out[(size_t)(c0 + rr + i) * R + r0 + cc] = (__bf16)t[cc][rr + i];
}

// ---------------------------------------------------------------- softmaxes
__global__ __launch_bounds__(256)
void softmax4k_kernel(float* __restrict__ P) {
    float* p = P + (size_t)blockIdx.x * 4096;
    float v[16];
    float mx = -INFINITY;
    #pragma unroll
    for (int i = 0; i < 16; i++) {
        v[i] = p[threadIdx.x + i * 256];
        mx = fmaxf(mx, v[i]);
    }
    mx = blockReduceMax256(mx);
    float s = 0.f;
    #pragma unroll
    for (int i = 0; i < 16; i++) { v[i] = __expf(v[i] - mx); s += v[i]; }
    s = blockReduceSum256(s);
    const float inv = 1.f / s;
    #pragma unroll
    for (int i = 0; i < 16; i++) p[threadIdx.x + i * 256] = v[i] * inv;
}

__global__ __launch_bounds__(256)
void softmax_fc_kernel(float* __restrict__ P) {
    float* p = P + (size_t)blockIdx.x * 32000;
    float m = -INFINITY, s = 0.f;
    for (int i = threadIdx.x; i < 32000; i += 256) {
        float v = p[i];
        if (v > m) { s = s * __expf(m - v) + 1.f; m = v; }
        else       { s += __expf(v - m); }
    }
    const float M = blockReduceMax256(m);
    s *= __expf(m - M);
    const float S = blockReduceSum256(s);
    const float inv = 1.f / S;
    for (int i = threadIdx.x; i < 32000; i += 256)
        p[i] = __expf(p[i] - M) * inv;
}

// ---------------------------------------------------------------- assemble s
__global__ __launch_bounds__(320)
void assemble_s_kernel(const int* __restrict__ X, const float* __restrict__ Emb,
                       const float* __restrict__ Cf, const float* __restrict__ Mo,
                       __bf16* __restrict__ S) {
    const int m = blockIdx.x;
    const int col = threadIdx.x * 4;
    float4 v;
    if (col < 256)      v = *(const float4*)(Emb + (size_t)X[m] * 256 + col);
    else if (col < 768) v = *(const float4*)(Cf + (size_t)m * 512 + (col - 256));
    else                v = *(const float4*)(Mo + (size_t)m * 512 + (col - 768));
    bf16x4 o;
    o[0] = (__bf16)v.x; o[1] = (__bf16)v.y; o[2] = (__bf16)v.z; o[3] = (__bf16)v.w;
    *(bf16x4*)(S + (size_t)m * 1280 + col) = o;
}

// ---------------------------------------------------------------- launch
extern "C" void kernel_launch(void* const* d_in, const int* in_sizes, int n_in,
                              void* d_out, int out_size, void* d_ws, size_t ws_size,
                              hipStream_t stream) {
    const int*   x    = (const int*)d_in[0];
    const int*   c    = (const int*)d_in[1];
    const float* emb  = (const float*)d_in[2];
    const float* w1 = (const float*)d_in[3],  *b1 = (const float*)d_in[4];
    const float* g1 = (const float*)d_in[5],  *be1 = (const float*)d_in[6];
    const float* w2 = (const float*)d_in[7],  *b2 = (const float*)d_in[8];
    const float* g2 = (const float*)d_in[9],  *be2 = (const float*)d_in[10];
    const float* w3 = (const float*)d_in[11], *b3 = (const float*)d_in[12];
    const float* g3 = (const float*)d_in[13], *be3 = (const float*)d_in[14];
    const float* w4 = (const float*)d_in[15], *b4 = (const float*)d_in[16];
    const float* g4 = (const float*)d_in[17], *be4 = (const float*)d_in[18];
    const float* w5 = (const float*)d_in[19], *b5 = (const float*)d_in[20];
    const float* g5 = (const float*)d_in[21], *be5 = (const float*)d_in[22];
    const float* fcW = (const float*)d_in[23], *fcb = (const float*)d_in[24];
    const float* memK = (const float*)d_in[25], *memV = (const float*)d_in[26];
    float* out = (float*)d_out;

    // -------- workspace --------
    char* W = (char*)d_ws;
    __bf16* fcWT_bf  = (__bf16*)(W + 0);            // 32000x1280 (81,920,000)
    __bf16* memK_bf  = (__bf16*)(W + 81920000);     // 4,194,304
    __bf16* memVT_bf = (__bf16*)(W + 86114304);     // 4,194,304
    __bf16* w5t      = (__bf16*)(W + 90308608);     // 512x3584  (3,670,016)
    __bf16* w4t      = (__bf16*)(W + 93978624);     // 256x1024  (524,288)
    __bf16* w3t      = (__bf16*)(W + 94502912);     // 128x512   (131,072)
    __bf16* w2t      = (__bf16*)(W + 94633984);     // 128x256   (65,536)
    __bf16* w1t      = (__bf16*)(W + 94699520);     // 128x512   (131,072)
    float*  SS       = (float*)(W + 94830592);      // 1024 f
    float*  BB       = (float*)(W + 94834688);      // 512 f
    float2* part     = (float2*)(W + 94836736);     // 131072 f2 (1,048,576)
    __bf16* YA = (__bf16*)(W + 95885312);           // 8,929,280
    __bf16* YB = (__bf16*)(W + 104814592);          // 9,453,568
    char* P = W + 114268160;                        // 34,340,864
    __bf16* Gt      = (__bf16*)P;
    float*  Pc5     = (float*)P;
    float*  scores  = (float*)P;
    __bf16* attn_bf = (__bf16*)(P + 16777216);
    float*  Pmo     = (float*)(P + 25165824);
    float*  cfeat    = (float*)(W + 148609024);
    __bf16* cfeat_bf = (__bf16*)(W + 150706176);
    float*  m_out    = (float*)(W + 151754752);
    __bf16* s_bf     = (__bf16*)(W + 153851904);

    __bf16* Y1 = YA; __bf16* Y3 = YA;
    __bf16* Y2 = YB; __bf16* Y4 = YB;

    // ---------------- weight prep ----------------
    transpose_cast_kernel<<<dim3(1000, 40), 256, 0, stream>>>(fcW, fcWT_bf, 1280, 32000);
    transpose_cast_kernel<<<dim3(16, 128), 256, 0, stream>>>(memV, memVT_bf, 4096, 512);
    cast_bf16_kernel<<<1024, 256, 0, stream>>>(memK, memK_bf, 262144);
    wt_fold_kernel<<<128, 256, 0, stream>>>(w1, b1, nullptr, w1t, BB, 32, 64, 8);
    gather_tr_kernel<<<1024, 256, 0, stream>>>(c, emb, Gt);

    // ---------------- conv1 ----------------
    mfma_gemm_bt<<<dim3(1024, 1), 256, 0, stream>>>(Gt, w1t, BB, Y1 + 64,
        32, 512, 512, 128, 0, 7, 16768LL, 4160, 0LL, 1.0f, 1, 0, 1);
    bn_stats_bf_kernel<32, 127, 130, 512><<<512, 256, 0, stream>>>(Y1, part);
    bn_finalize_kernel<<<32, 64, 0, stream>>>(part, g1, be1, SS, 32, 512,
                                              1.0f / (1024.f * 127.f));
    padfill_kernel<<<1024, 256, 0, stream>>>(Y1, SS, 32, 130,
                                             make_int4(0, 1, 129, 0), 3);
    wt_fold_kernel<<<128, 256, 0, stream>>>(w2, b2, SS, w2t, BB, 64, 32, 8);

    // ---------------- conv2 ----------------
    mfma_gemm_bt<<<dim3(512, 1), 256, 0, stream>>>(Y1, w2t, BB, Y2 + 128,
        64, 256, 256, 64, 4160, 6, 8320LL, 4224, 0LL, 1.0f, 1, 0, 1);
    bn_stats_bf_kernel<64, 62, 66, 256><<<256, 256, 0, stream>>>(Y2, part);
    bn_finalize_kernel<<<64, 64, 0, stream>>>(part, g2, be2, SS, 64, 256,
                                              1.0f / (1024.f * 62.f));
    padfill_kernel<<<1024, 256, 0, stream>>>(Y2, SS, 64, 66,
                                             make_int4(0, 1, 64, 65), 4);
    wt_fold_kernel<<<128, 256, 0, stream>>>(w3, b3, SS, w3t, BB, 128, 64, 8);

    // ---------------- conv3 ----------------
    mfma_gemm_bt<<<dim3(256, 1), 256, 0, stream>>>(Y2, w3t, BB, Y3 + 256,
        128, 512, 512, 128, 4224, 5, 16896LL, 4352, 0LL, 1.0f, 1, 0, 1);
    bn_stats_bf_kernel<128, 30, 34, 256><<<256, 256, 0, stream>>>(Y3, part);
    bn_finalize_kernel<<<128, 64, 0, stream>>>(part, g3, be3, SS, 128, 256,
                                               1.0f / (1024.f * 30.f));
    padfill_kernel<<<1024, 256, 0, stream>>>(Y3, SS, 128, 34,
                                             make_int4(0, 1, 32, 33), 4);
    wt_fold_kernel<<<256, 256, 0, stream>>>(w4, b4, SS, w4t, BB, 256, 128, 8);

    // ---------------- conv4 ----------------
    mfma_gemm_bt<<<dim3(128, 2), 256, 0, stream>>>(Y3, w4t, BB, Y4 + 512,
        256, 1024, 1024, 256, 4352, 4, 34816LL, 4608, 0LL, 1.0f, 1, 0, 1);
    bn_stats_bf_kernel<256, 14, 18, 256><<<256, 256, 0, stream>>>(Y4, part);
    bn_finalize_kernel<<<256, 64, 0, stream>>>(part, g4, be4, SS, 256, 256,
                                               1.0f / (1024.f * 14.f));
    wt_fold_kernel<<<512, 256, 0, stream>>>(w5, b5, SS, w5t, BB, 512, 256, 14);

    // ---------------- conv5 (split-K 8) ----------------
    mfma_gemm_bt<<<dim3(8, 4, 8), 256, 0, stream>>>(Y4 + 512, w5t, nullptr, Pc5,
        512, 3584, 448, 4608, 0, 7, 589824LL, 65536, 524288LL, 1.0f, 0, 0, 0);
    splitk_reduce_kernel<<<512, 256, 0, stream>>>(Pc5, cfeat, BB, 8, 524288, 512, 1);
    bn_stats_cf_kernel<<<256, 256, 0, stream>>>(cfeat, part);
    bn_finalize_kernel<<<512, 64, 0, stream>>>(part, g5, be5, SS, 512, 256,
                                               1.0f / 1024.f);
    bn_apply_both_kernel<<<512, 256, 0, stream>>>(cfeat, cfeat_bf, SS, 131072);

    // ---------------- attention over memory ----------------
    mfma_gemm_bt<<<dim3(8, 32), 256, 0, stream>>>(cfeat_bf, memK_bf, nullptr, scores,
        4096, 512, 512, 512, 0, 7, 65536LL, 524288, 0LL,
        0.04419417382415922f, 0, 1, 0);
    softmax4k_kernel<<<1024, 256, 0, stream>>>(scores);
    cast_bf16_kernel<<<2048, 256, 0, stream>>>(scores, attn_bf, 524288);
    mfma_gemm_bt<<<dim3(8, 4, 4), 256, 0, stream>>>(attn_bf, memVT_bf, nullptr, Pmo,
        512, 4096, 1024, 4096, 0, 7, 524288LL, 65536, 524288LL, 1.0f, 0, 0, 0);
    splitk_reduce_kernel<<<512, 256, 0, stream>>>(Pmo, m_out, nullptr, 4, 524288, 512, 0);

    // ---------------- concat + fc + softmax ----------------
    assemble_s_kernel<<<1024, 320, 0, stream>>>(x, emb, cfeat, m_out, s_bf);
    mfma_gemm256_bt<<<dim3(500), 512, 0, stream>>>(s_bf, fcWT_bf, fcb, out,
                                                   1024, 32000, 1280, 500);
    softmax_fc_kernel<<<1024, 256, 0, stream>>>(out);
}